// Round 2
// baseline (11670.786 us; speedup 1.0000x reference)
//
#include <hip/hip_runtime.h>

// Problem constants (from setup_inputs): B=4,S=128,E=512,H=8,Dh=64,V=32000,M=16,T=144,L=2,FF=2048
#define BB 4
#define SS 128
#define EE 512
#define HH 8
#define VV 32000
#define MM 16
#define TT 144
#define LL 2
#define FFF 2048

// ---------------------------------------------------------------------------
// Tiled f32 GEMM:  C[M,N] = A[M,K] @ W[N,K]^T + bias, optional relu.
// A row r is A + r*lda, or (gather) A + Aidx[r]*lda.  C has row stride ldc
// (C pointer may be pre-offset for column-block writes, e.g. kv into qkv+512).
// M,N multiples of 64; K multiple of 16.  64x64 tile, 256 thr, 4x4 microtile.
// ---------------------------------------------------------------------------
__global__ __launch_bounds__(256, 2) void gemm_nt(
    const float* __restrict__ A, const int* __restrict__ Aidx, int lda,
    const float* __restrict__ W, const float* __restrict__ bias,
    float* __restrict__ C, int ldc, int M, int N, int K, int relu)
{
    __shared__ float As[16][68];
    __shared__ float Ws[16][68];
    const int tid = threadIdx.x;
    const int tx = tid & 15, ty = tid >> 4;
    const int m0 = blockIdx.x * 64, n0 = blockIdx.y * 64;
    const int lrow = tid >> 2;          // 0..63
    const int lk = (tid & 3) << 2;      // 0,4,8,12
    const float* Arow;
    if (Aidx) Arow = A + (size_t)Aidx[m0 + lrow] * lda;
    else      Arow = A + (size_t)(m0 + lrow) * lda;
    const float* Wrow = W + (size_t)(n0 + lrow) * K;

    float acc[4][4];
#pragma unroll
    for (int i = 0; i < 4; i++)
#pragma unroll
        for (int j = 0; j < 4; j++) acc[i][j] = 0.f;

    for (int k0 = 0; k0 < K; k0 += 16) {
        const float4 av = *(const float4*)(Arow + k0 + lk);
        const float4 wv = *(const float4*)(Wrow + k0 + lk);
        __syncthreads();
        As[lk + 0][lrow] = av.x; As[lk + 1][lrow] = av.y;
        As[lk + 2][lrow] = av.z; As[lk + 3][lrow] = av.w;
        Ws[lk + 0][lrow] = wv.x; Ws[lk + 1][lrow] = wv.y;
        Ws[lk + 2][lrow] = wv.z; Ws[lk + 3][lrow] = wv.w;
        __syncthreads();
#pragma unroll
        for (int k = 0; k < 16; k++) {
            const float4 a = *(const float4*)(&As[k][ty << 2]);
            const float4 bq = *(const float4*)(&Ws[k][tx << 2]);
            acc[0][0] += a.x * bq.x; acc[0][1] += a.x * bq.y; acc[0][2] += a.x * bq.z; acc[0][3] += a.x * bq.w;
            acc[1][0] += a.y * bq.x; acc[1][1] += a.y * bq.y; acc[1][2] += a.y * bq.z; acc[1][3] += a.y * bq.w;
            acc[2][0] += a.z * bq.x; acc[2][1] += a.z * bq.y; acc[2][2] += a.z * bq.z; acc[2][3] += a.z * bq.w;
            acc[3][0] += a.w * bq.x; acc[3][1] += a.w * bq.y; acc[3][2] += a.w * bq.z; acc[3][3] += a.w * bq.w;
        }
    }

    float4 bv = make_float4(0.f, 0.f, 0.f, 0.f);
    if (bias) bv = *(const float4*)(bias + n0 + (tx << 2));
#pragma unroll
    for (int i = 0; i < 4; i++) {
        const int r = m0 + (ty << 2) + i;
        float4 o;
        o.x = acc[i][0] + bv.x; o.y = acc[i][1] + bv.y;
        o.z = acc[i][2] + bv.z; o.w = acc[i][3] + bv.w;
        if (relu) {
            o.x = fmaxf(o.x, 0.f); o.y = fmaxf(o.y, 0.f);
            o.z = fmaxf(o.z, 0.f); o.w = fmaxf(o.w, 0.f);
        }
        *(float4*)(C + (size_t)r * ldc + n0 + (tx << 2)) = o;
    }
}

// ---------------------------------------------------------------------------
// Attention: qkv layout [B, T, 1536] (q cols 0..511, k 512..1023, v 1024..1535,
// head h at cols h*64..h*64+63).  out [B, T, 512].  One block = (qtile16, h, b).
// MODE: 0 = none, 1 = causal (key j > qpos masked), 2 = keylimit (j >= cur).
// Additive mask -1e9 to match the reference exactly.
// TK/MODE are template params so score array s[] is statically indexed
// (rule #20: runtime-indexed local arrays go to scratch).
// ---------------------------------------------------------------------------
template<int TK, int MODE>
__global__ __launch_bounds__(256) void attn_kernel(
    const float* __restrict__ qkv, float* __restrict__ out,
    int T, int cur)
{
    __shared__ float Ks[TT][68];
    __shared__ float Qs[16][68];
    __shared__ float Ps[16][160];
    const int tid = threadIdx.x;
    const int tx = tid & 15, ty = tid >> 4;
    const int q0 = blockIdx.x * 16;
    const int h = blockIdx.y, b = blockIdx.z;
    const size_t base = (size_t)b * T * 1536;

    for (int idx = tid; idx < TK * 64; idx += 256) {
        const int j = idx >> 6, d = idx & 63;
        Ks[j][d] = qkv[base + (size_t)j * 1536 + 512 + h * 64 + d];
    }
    for (int idx = tid; idx < 16 * 64; idx += 256) {
        const int j = idx >> 6, d = idx & 63;
        Qs[j][d] = qkv[base + (size_t)(q0 + j) * 1536 + h * 64 + d];
    }
    __syncthreads();

    const int qpos = q0 + ty;
    constexpr int NJ = (TK + 15) >> 4;
    float s[NJ];
#pragma unroll
    for (int jj = 0; jj < NJ; jj++) {
        const int j = tx + (jj << 4);
        float acc = 0.f;
#pragma unroll
        for (int d = 0; d < 64; d += 4) {
            const float4 qv = *(const float4*)(&Qs[ty][d]);
            const float4 kv = *(const float4*)(&Ks[j][d]);
            acc += qv.x * kv.x + qv.y * kv.y + qv.z * kv.z + qv.w * kv.w;
        }
        acc *= 0.125f;  // 1/sqrt(64)
        if (MODE == 1 && j > qpos) acc += -1e9f;
        if (MODE == 2 && j >= cur) acc += -1e9f;
        s[jj] = acc;
    }
    // wave-parallel softmax across the 16-lane tx group (same q row)
    float m = s[0];
#pragma unroll
    for (int jj = 1; jj < NJ; jj++) m = fmaxf(m, s[jj]);
#pragma unroll
    for (int o = 8; o >= 1; o >>= 1) m = fmaxf(m, __shfl_xor(m, o, 16));
    float sum = 0.f;
#pragma unroll
    for (int jj = 0; jj < NJ; jj++) {
        const float e = expf(s[jj] - m);
        s[jj] = e;
        sum += e;
    }
#pragma unroll
    for (int o = 8; o >= 1; o >>= 1) sum += __shfl_xor(sum, o, 16);
    const float inv = 1.f / sum;
#pragma unroll
    for (int jj = 0; jj < NJ; jj++) {
        const int j = tx + (jj << 4);
        Ps[ty][j] = s[jj] * inv;
    }
    __syncthreads();

    // O[ty][tx*4..+3] = sum_j P[ty][j] * V[j][tx*4..+3]
    float4 o4 = make_float4(0.f, 0.f, 0.f, 0.f);
    const float* Vb = qkv + base + 1024 + h * 64 + (tx << 2);
#pragma unroll 4
    for (int j = 0; j < TK; j++) {
        const float p = Ps[ty][j];
        const float4 v = *(const float4*)(Vb + (size_t)j * 1536);
        o4.x = fmaf(p, v.x, o4.x); o4.y = fmaf(p, v.y, o4.y);
        o4.z = fmaf(p, v.z, o4.z); o4.w = fmaf(p, v.w, o4.w);
    }
    *(float4*)(out + (size_t)(b * T + q0 + ty) * EE + h * 64 + (tx << 2)) = o4;
}

// ---------------------------------------------------------------------------
// out[r] = LN(X[r] + Sa[r]) * g + b   (one wave per 512-wide row)
// ---------------------------------------------------------------------------
__global__ __launch_bounds__(64) void resln_kernel(
    const float* __restrict__ X, const float* __restrict__ Sa,
    const float* __restrict__ g, const float* __restrict__ bta,
    float* __restrict__ out)
{
    const int r = blockIdx.x;
    const int l = threadIdx.x;
    const float* xr = X + (size_t)r * EE;
    const float* sr = Sa + (size_t)r * EE;
    float4 v[2];
    float sum = 0.f;
#pragma unroll
    for (int p = 0; p < 2; p++) {
        const int o = p * 256 + l * 4;
        const float4 a = *(const float4*)(xr + o);
        const float4 c = *(const float4*)(sr + o);
        v[p] = make_float4(a.x + c.x, a.y + c.y, a.z + c.z, a.w + c.w);
        sum += v[p].x + v[p].y + v[p].z + v[p].w;
    }
#pragma unroll
    for (int o = 32; o >= 1; o >>= 1) sum += __shfl_xor(sum, o, 64);
    const float mean = sum * (1.f / EE);
    float vs = 0.f;
#pragma unroll
    for (int p = 0; p < 2; p++) {
        const float dx = v[p].x - mean, dy = v[p].y - mean;
        const float dz = v[p].z - mean, dw = v[p].w - mean;
        vs += dx * dx + dy * dy + dz * dz + dw * dw;
    }
#pragma unroll
    for (int o = 32; o >= 1; o >>= 1) vs += __shfl_xor(vs, o, 64);
    const float rstd = 1.f / sqrtf(vs * (1.f / EE) + 1e-5f);
#pragma unroll
    for (int p = 0; p < 2; p++) {
        const int o = p * 256 + l * 4;
        const float4 gv = *(const float4*)(g + o);
        const float4 bv = *(const float4*)(bta + o);
        float4 ov;
        ov.x = (v[p].x - mean) * rstd * gv.x + bv.x;
        ov.y = (v[p].y - mean) * rstd * gv.y + bv.y;
        ov.z = (v[p].z - mean) * rstd * gv.z + bv.z;
        ov.w = (v[p].w - mean) * rstd * gv.w + bv.w;
        *(float4*)(out + (size_t)r * EE + o) = ov;
    }
}

// src = LN(embedding[seq] + pos_emb[s]) — one wave per (b,s) row
__global__ __launch_bounds__(64) void embed_ln_kernel(
    const int* __restrict__ seq, const float* __restrict__ emb,
    const float* __restrict__ pemb, const float* __restrict__ g,
    const float* __restrict__ bta, float* __restrict__ out)
{
    const int r = blockIdx.x;           // b*S + s
    const int s = r & (SS - 1);
    const int l = threadIdx.x;
    const int tok = seq[r];
    const float* er = emb + (size_t)tok * EE;
    const float* pr = pemb + (size_t)s * EE;
    float4 v[2];
    float sum = 0.f;
#pragma unroll
    for (int p = 0; p < 2; p++) {
        const int o = p * 256 + l * 4;
        const float4 a = *(const float4*)(er + o);
        const float4 c = *(const float4*)(pr + o);
        v[p] = make_float4(a.x + c.x, a.y + c.y, a.z + c.z, a.w + c.w);
        sum += v[p].x + v[p].y + v[p].z + v[p].w;
    }
#pragma unroll
    for (int o = 32; o >= 1; o >>= 1) sum += __shfl_xor(sum, o, 64);
    const float mean = sum * (1.f / EE);
    float vs = 0.f;
#pragma unroll
    for (int p = 0; p < 2; p++) {
        const float dx = v[p].x - mean, dy = v[p].y - mean;
        const float dz = v[p].z - mean, dw = v[p].w - mean;
        vs += dx * dx + dy * dy + dz * dz + dw * dw;
    }
#pragma unroll
    for (int o = 32; o >= 1; o >>= 1) vs += __shfl_xor(vs, o, 64);
    const float rstd = 1.f / sqrtf(vs * (1.f / EE) + 1e-5f);
#pragma unroll
    for (int p = 0; p < 2; p++) {
        const int o = p * 256 + l * 4;
        const float4 gv = *(const float4*)(g + o);
        const float4 bv = *(const float4*)(bta + o);
        float4 ov;
        ov.x = (v[p].x - mean) * rstd * gv.x + bv.x;
        ov.y = (v[p].y - mean) * rstd * gv.y + bv.y;
        ov.z = (v[p].z - mean) * rstd * gv.z + bv.z;
        ov.w = (v[p].w - mean) * rstd * gv.w + bv.w;
        *(float4*)(out + (size_t)r * EE + o) = ov;
    }
}

// buf[:, :S] = xe ; buf[:, S:] = 0
__global__ void bufinit_kernel(const float* __restrict__ xe, float* __restrict__ buf)
{
    const int idx = blockIdx.x * 256 + threadIdx.x;
    if (idx < BB * TT * EE) {
        const int e = idx & (EE - 1);
        const int t = (idx >> 9) % TT;
        const int b = idx / (EE * TT);
        buf[idx] = (t < SS) ? xe[((size_t)b * SS + t) * EE + e] : 0.f;
    }
}

// logits[b][col] = dot(tgt[b, cur-1, :], fo_w[col, :]) + fo_b[col]
// one wave per column, 4 batch accumulators
__global__ __launch_bounds__(256) void logits_kernel(
    const float* __restrict__ tgt, const float* __restrict__ foW,
    const float* __restrict__ fob, float* __restrict__ logits, int cur)
{
    __shared__ float last_s[BB][EE];
    const int tid = threadIdx.x;
    for (int idx = tid; idx < BB * EE; idx += 256) {
        const int b = idx >> 9, e = idx & (EE - 1);
        last_s[b][e] = tgt[((size_t)b * TT + (cur - 1)) * EE + e];
    }
    __syncthreads();
    const int w = tid >> 6, l = tid & 63;
    const int col = blockIdx.x * 4 + w;
    float a0 = 0.f, a1 = 0.f, a2 = 0.f, a3 = 0.f;
    const float* wr = foW + (size_t)col * EE;
#pragma unroll
    for (int p = 0; p < 2; p++) {
        const int o = p * 256 + l * 4;
        const float4 wv = *(const float4*)(wr + o);
        const float4 l0 = *(const float4*)(&last_s[0][o]);
        const float4 l1 = *(const float4*)(&last_s[1][o]);
        const float4 l2 = *(const float4*)(&last_s[2][o]);
        const float4 l3 = *(const float4*)(&last_s[3][o]);
        a0 += wv.x * l0.x + wv.y * l0.y + wv.z * l0.z + wv.w * l0.w;
        a1 += wv.x * l1.x + wv.y * l1.y + wv.z * l1.z + wv.w * l1.w;
        a2 += wv.x * l2.x + wv.y * l2.y + wv.z * l2.z + wv.w * l2.w;
        a3 += wv.x * l3.x + wv.y * l3.y + wv.z * l3.z + wv.w * l3.w;
    }
#pragma unroll
    for (int o = 32; o >= 1; o >>= 1) {
        a0 += __shfl_xor(a0, o, 64); a1 += __shfl_xor(a1, o, 64);
        a2 += __shfl_xor(a2, o, 64); a3 += __shfl_xor(a3, o, 64);
    }
    if (l == 0) {
        const float bb = fob[col];
        logits[(size_t)0 * VV + col] = a0 + bb;
        logits[(size_t)1 * VV + col] = a1 + bb;
        logits[(size_t)2 * VV + col] = a2 + bb;
        logits[(size_t)3 * VV + col] = a3 + bb;
    }
}

// argmax over V (first-index tie-break, numpy semantics), write token,
// and append embedding[tok] at buf[b, cur, :]
__global__ __launch_bounds__(256) void argmax_kernel(
    const float* __restrict__ logits, const float* __restrict__ emb,
    float* __restrict__ buf, int* __restrict__ out_tok, int cur, int step)
{
    __shared__ float sv[256];
    __shared__ int si[256];
    const int b = blockIdx.x;
    const int tid = threadIdx.x;
    float best = -3.4e38f;
    int bi = 0x7fffffff;
    for (int v = tid; v < VV; v += 256) {
        const float x = logits[(size_t)b * VV + v];
        if (x > best) { best = x; bi = v; }
    }
    sv[tid] = best; si[tid] = bi;
    __syncthreads();
    for (int s = 128; s > 0; s >>= 1) {
        if (tid < s) {
            const float xo = sv[tid + s]; const int io = si[tid + s];
            if (xo > sv[tid] || (xo == sv[tid] && io < si[tid])) { sv[tid] = xo; si[tid] = io; }
        }
        __syncthreads();
    }
    const int tok = si[0];
    if (tid == 0) out_tok[b * MM + step] = tok;
    for (int e = tid; e < EE; e += 256)
        buf[((size_t)b * TT + cur) * EE + e] = emb[(size_t)tok * EE + e];
}

extern "C" void kernel_launch(void* const* d_in, const int* in_sizes, int n_in,
                              void* d_out, int out_size, void* d_ws, size_t ws_size,
                              hipStream_t stream)
{
    (void)in_sizes; (void)n_in; (void)out_size; (void)ws_size;
    const int*   seq   = (const int*)d_in[0];
    const int*   ptag  = (const int*)d_in[1];
    const int*   ntag  = (const int*)d_in[2];
    const float* emb   = (const float*)d_in[4];
    const float* pemb  = (const float*)d_in[5];
    const float* fcp_w = (const float*)d_in[6];
    const float* fcp_b = (const float*)d_in[7];
    const float* fcn_w = (const float*)d_in[8];
    const float* fcn_b = (const float*)d_in[9];
    const float* ln_g  = (const float*)d_in[10];
    const float* ln_b  = (const float*)d_in[11];
    const float* asi_w = (const float*)d_in[12];
    const float* asi_b = (const float*)d_in[13];
    const float* aso_w = (const float*)d_in[14];
    const float* aso_b = (const float*)d_in[15];
    const float* api_w = (const float*)d_in[16];
    const float* api_b = (const float*)d_in[17];
    const float* apo_w = (const float*)d_in[18];
    const float* apo_b = (const float*)d_in[19];
    const float* ani_w = (const float*)d_in[20];
    const float* ani_b = (const float*)d_in[21];
    const float* ano_w = (const float*)d_in[22];
    const float* ano_b = (const float*)d_in[23];
    const float* dsi_w = (const float*)d_in[24];
    const float* dsi_b = (const float*)d_in[25];
    const float* dso_w = (const float*)d_in[26];
    const float* dso_b = (const float*)d_in[27];
    const float* dci_w = (const float*)d_in[28];
    const float* dci_b = (const float*)d_in[29];
    const float* dco_w = (const float*)d_in[30];
    const float* dco_b = (const float*)d_in[31];
    const float* d1_w  = (const float*)d_in[32];
    const float* d1_b  = (const float*)d_in[33];
    const float* d2_w  = (const float*)d_in[34];
    const float* d2_b  = (const float*)d_in[35];
    const float* dln_g = (const float*)d_in[36];
    const float* dln_b = (const float*)d_in[37];
    const float* fo_w  = (const float*)d_in[38];
    const float* fo_b  = (const float*)d_in[39];
    int* out_tok = (int*)d_out;

    // workspace layout (floats); total ~17.7 MB
    float* ws  = (float*)d_ws;
    float* qkv = ws;                    // [B*T, 1536]   884736
    float* att = qkv + 884736;          // [B*T, 512]    294912
    float* sab = att + 294912;          // [B*T, 512]    294912
    float* tgt = sab + 294912;          // [B*T, 512]    294912
    float* buf = tgt + 294912;          // [B*T, 512]    294912
    float* ffb = buf + 294912;          // [B*T, 2048]  1179648
    float* lg  = ffb + 1179648;         // [B, V]        128000
    float* src = lg + 128000;           // [B*S, 512]    262144
    float* xe  = src + 262144;          // [B*S, 512]    262144
    float* pf  = xe + 262144;           // [B*S, 512]    262144
    float* nf  = pf + 262144;           // [B*S, 512]    262144

    const int RS = BB * SS;   // 512 encoder rows
    const int RT = BB * TT;   // 576 decoder rows

    // ---------------- encoder ----------------
    embed_ln_kernel<<<RS, 64, 0, stream>>>(seq, emb, pemb, ln_g, ln_b, src);
    // pf = embedding[pos_tags] @ fc_pos_w^T + b ; nf likewise (gathered A)
    gemm_nt<<<dim3(RS / 64, 8), 256, 0, stream>>>(emb, ptag, EE, fcp_w, fcp_b, pf, EE, RS, 512, EE, 0);
    gemm_nt<<<dim3(RS / 64, 8), 256, 0, stream>>>(emb, ntag, EE, fcn_w, fcn_b, nf, EE, RS, 512, EE, 0);
    // self-attn (no mask, no residual/LN in encoder blocks)
    gemm_nt<<<dim3(RS / 64, 24), 256, 0, stream>>>(src, nullptr, EE, asi_w, asi_b, qkv, 1536, RS, 1536, EE, 0);
    attn_kernel<SS, 0><<<dim3(SS / 16, HH, BB), 256, 0, stream>>>(qkv, att, SS, 0);
    gemm_nt<<<dim3(RS / 64, 8), 256, 0, stream>>>(att, nullptr, EE, aso_w, aso_b, xe, EE, RS, 512, EE, 0);
    // cross-attn vs pos features
    gemm_nt<<<dim3(RS / 64, 8), 256, 0, stream>>>(xe, nullptr, EE, api_w, api_b, qkv, 1536, RS, 512, EE, 0);
    gemm_nt<<<dim3(RS / 64, 16), 256, 0, stream>>>(pf, nullptr, EE, api_w + 512 * EE, api_b + 512, qkv + 512, 1536, RS, 1024, EE, 0);
    attn_kernel<SS, 0><<<dim3(SS / 16, HH, BB), 256, 0, stream>>>(qkv, att, SS, 0);
    gemm_nt<<<dim3(RS / 64, 8), 256, 0, stream>>>(att, nullptr, EE, apo_w, apo_b, src, EE, RS, 512, EE, 0);
    // cross-attn vs ner features
    gemm_nt<<<dim3(RS / 64, 8), 256, 0, stream>>>(src, nullptr, EE, ani_w, ani_b, qkv, 1536, RS, 512, EE, 0);
    gemm_nt<<<dim3(RS / 64, 16), 256, 0, stream>>>(nf, nullptr, EE, ani_w + 512 * EE, ani_b + 512, qkv + 512, 1536, RS, 1024, EE, 0);
    attn_kernel<SS, 0><<<dim3(SS / 16, HH, BB), 256, 0, stream>>>(qkv, att, SS, 0);
    gemm_nt<<<dim3(RS / 64, 8), 256, 0, stream>>>(att, nullptr, EE, ano_w, ano_b, xe, EE, RS, 512, EE, 0);
    // buf[:, :S] = xe ; rest zero
    bufinit_kernel<<<(BB * TT * EE + 255) / 256, 256, 0, stream>>>(xe, buf);

    // ---------------- decoder generation loop (host-unrolled, M=16) ----------------
    for (int i = 0; i < MM; i++) {
        const int cur = SS + i;
        for (int l = 0; l < LL; l++) {
            const float* tin = (l == 0) ? buf : tgt;
            // self-attn (causal)
            gemm_nt<<<dim3(RT / 64, 24), 256, 0, stream>>>(tin, nullptr, EE,
                dsi_w + (size_t)l * 1536 * EE, dsi_b + l * 1536, qkv, 1536, RT, 1536, EE, 0);
            attn_kernel<TT, 1><<<dim3(TT / 16, HH, BB), 256, 0, stream>>>(qkv, att, TT, 0);
            gemm_nt<<<dim3(RT / 64, 8), 256, 0, stream>>>(att, nullptr, EE,
                dso_w + (size_t)l * EE * EE, dso_b + l * EE, sab, EE, RT, 512, EE, 0);
            resln_kernel<<<RT, 64, 0, stream>>>(tin, sab, dln_g + (l * 3 + 0) * EE, dln_b + (l * 3 + 0) * EE, tgt);
            // cross-attn (mem = buf, keys < cur)
            gemm_nt<<<dim3(RT / 64, 8), 256, 0, stream>>>(tgt, nullptr, EE,
                dci_w + (size_t)l * 1536 * EE, dci_b + l * 1536, qkv, 1536, RT, 512, EE, 0);
            gemm_nt<<<dim3(RT / 64, 16), 256, 0, stream>>>(buf, nullptr, EE,
                dci_w + (size_t)l * 1536 * EE + 512 * EE, dci_b + l * 1536 + 512, qkv + 512, 1536, RT, 1024, EE, 0);
            attn_kernel<TT, 2><<<dim3(TT / 16, HH, BB), 256, 0, stream>>>(qkv, att, TT, cur);
            gemm_nt<<<dim3(RT / 64, 8), 256, 0, stream>>>(att, nullptr, EE,
                dco_w + (size_t)l * EE * EE, dco_b + l * EE, sab, EE, RT, 512, EE, 0);
            resln_kernel<<<RT, 64, 0, stream>>>(tgt, sab, dln_g + (l * 3 + 1) * EE, dln_b + (l * 3 + 1) * EE, tgt);
            // FFN
            gemm_nt<<<dim3(RT / 64, 32), 256, 0, stream>>>(tgt, nullptr, EE,
                d1_w + (size_t)l * FFF * EE, d1_b + l * FFF, ffb, FFF, RT, FFF, EE, 1);
            gemm_nt<<<dim3(RT / 64, 8), 256, 0, stream>>>(ffb, nullptr, FFF,
                d2_w + (size_t)l * EE * FFF, d2_b + l * EE, sab, EE, RT, 512, FFF, 0);
            resln_kernel<<<RT, 64, 0, stream>>>(tgt, sab, dln_g + (l * 3 + 2) * EE, dln_b + (l * 3 + 2) * EE, tgt);
        }
        logits_kernel<<<VV / 4, 256, 0, stream>>>(tgt, fo_w, fo_b, lg, cur);
        argmax_kernel<<<BB, 256, 0, stream>>>(lg, emb, buf, out_tok, cur, i);
    }
}

// Round 4
// 6841.032 us; speedup vs baseline: 1.7060x; 1.7060x over previous
//
#include <hip/hip_runtime.h>

// Problem constants: B=4,S=128,E=512,H=8,Dh=64,V=32000,M=16,T=144,L=2,FF=2048
#define BB 4
#define SS 128
#define EE 512
#define HH 8
#define VV 32000
#define MM 16
#define TT 144
#define LL 2
#define FFF 2048

// ---------------------------------------------------------------------------
// Split-K tiled f32 GEMM: Cp[z] = A[M,Kslice_z] @ W[N,Kslice_z]^T (+bias if z==0)
// z = blockIdx.z in [0,4); slice k-range [z*Kslice, (z+1)*Kslice).
// Consumers sum the 4 partial slices (deterministic order — no atomics).
// A row r is A + r*lda, or (gather) A + Aidx[r]*lda.  C row stride ldc;
// partial slice stride pstride (elements).  64x64 tile, 256 thr, 4x4 micro.
// ---------------------------------------------------------------------------
__global__ __launch_bounds__(256, 2) void gemm_nt(
    const float* __restrict__ A, const int* __restrict__ Aidx, int lda,
    const float* __restrict__ W, const float* __restrict__ bias,
    float* __restrict__ C, int ldc, size_t pstride, int K, int Kslice)
{
    __shared__ float As[16][68];
    __shared__ float Ws[16][68];
    const int tid = threadIdx.x;
    const int tx = tid & 15, ty = tid >> 4;
    const int m0 = blockIdx.x * 64, n0 = blockIdx.y * 64;
    const int z = blockIdx.z;
    const int lrow = tid >> 2;          // 0..63
    const int lk = (tid & 3) << 2;      // 0,4,8,12
    const float* Arow;
    if (Aidx) Arow = A + (size_t)Aidx[m0 + lrow] * lda;
    else      Arow = A + (size_t)(m0 + lrow) * lda;
    const float* Wrow = W + (size_t)(n0 + lrow) * K;

    float acc[4][4];
#pragma unroll
    for (int i = 0; i < 4; i++)
#pragma unroll
        for (int j = 0; j < 4; j++) acc[i][j] = 0.f;

    const int kbeg = z * Kslice, kend = kbeg + Kslice;
    for (int k0 = kbeg; k0 < kend; k0 += 16) {
        const float4 av = *(const float4*)(Arow + k0 + lk);
        const float4 wv = *(const float4*)(Wrow + k0 + lk);
        __syncthreads();
        As[lk + 0][lrow] = av.x; As[lk + 1][lrow] = av.y;
        As[lk + 2][lrow] = av.z; As[lk + 3][lrow] = av.w;
        Ws[lk + 0][lrow] = wv.x; Ws[lk + 1][lrow] = wv.y;
        Ws[lk + 2][lrow] = wv.z; Ws[lk + 3][lrow] = wv.w;
        __syncthreads();
#pragma unroll
        for (int k = 0; k < 16; k++) {
            const float4 a = *(const float4*)(&As[k][ty << 2]);
            const float4 bq = *(const float4*)(&Ws[k][tx << 2]);
            acc[0][0] += a.x * bq.x; acc[0][1] += a.x * bq.y; acc[0][2] += a.x * bq.z; acc[0][3] += a.x * bq.w;
            acc[1][0] += a.y * bq.x; acc[1][1] += a.y * bq.y; acc[1][2] += a.y * bq.z; acc[1][3] += a.y * bq.w;
            acc[2][0] += a.z * bq.x; acc[2][1] += a.z * bq.y; acc[2][2] += a.z * bq.z; acc[2][3] += a.z * bq.w;
            acc[3][0] += a.w * bq.x; acc[3][1] += a.w * bq.y; acc[3][2] += a.w * bq.z; acc[3][3] += a.w * bq.w;
        }
    }

    float4 bv = make_float4(0.f, 0.f, 0.f, 0.f);
    if (bias && z == 0) bv = *(const float4*)(bias + n0 + (tx << 2));
    float* Cz = C + z * pstride;
#pragma unroll
    for (int i = 0; i < 4; i++) {
        const int r = m0 + (ty << 2) + i;
        float4 o;
        o.x = acc[i][0] + bv.x; o.y = acc[i][1] + bv.y;
        o.z = acc[i][2] + bv.z; o.w = acc[i][3] + bv.w;
        *(float4*)(Cz + (size_t)r * ldc + n0 + (tx << 2)) = o;
    }
}

// out[i] = maybe_relu(p0[i]+p1[i]+p2[i]+p3[i])  (float4 granularity, n4 vecs)
__global__ __launch_bounds__(256) void reduce4_kernel(
    const float* __restrict__ P, size_t pstride,
    float* __restrict__ out, int n4, int relu)
{
    int i = blockIdx.x * 256 + threadIdx.x;
    const int stride = gridDim.x * 256;
    for (; i < n4; i += stride) {
        const float4 a = ((const float4*)P)[i];
        const float4 b = ((const float4*)(P + pstride))[i];
        const float4 c = ((const float4*)(P + 2 * pstride))[i];
        const float4 d = ((const float4*)(P + 3 * pstride))[i];
        float4 o;
        o.x = a.x + b.x + c.x + d.x; o.y = a.y + b.y + c.y + d.y;
        o.z = a.z + b.z + c.z + d.z; o.w = a.w + b.w + c.w + d.w;
        if (relu) {
            o.x = fmaxf(o.x, 0.f); o.y = fmaxf(o.y, 0.f);
            o.z = fmaxf(o.z, 0.f); o.w = fmaxf(o.w, 0.f);
        }
        ((float4*)out)[i] = o;
    }
}

// ---------------------------------------------------------------------------
// Attention over split-K qkv partials (sums 4 slices at stage time).
// qkvP layout per slice: [B, T, 1536] (q 0..511, k 512..1023, v 1024..1535).
// out [B, T, 512].  Block = (qtile16, h, b).  MODE: 0 none, 1 causal, 2 keylim.
// V re-uses the K LDS tile after scores (barrier-separated).
// ---------------------------------------------------------------------------
template<int TK, int MODE>
__global__ __launch_bounds__(256) void attn_kernel(
    const float* __restrict__ qkvP, size_t pstride, float* __restrict__ out,
    int T, int cur)
{
    __shared__ float KVs[TK][68];
    __shared__ float Qs[16][68];
    __shared__ float Ps[16][TK + 4];
    const int tid = threadIdx.x;
    const int tx = tid & 15, ty = tid >> 4;
    const int q0 = blockIdx.x * 16;
    const int h = blockIdx.y, b = blockIdx.z;
    const size_t base = (size_t)b * T * 1536 + h * 64;

    // stage K = sum of 4 partial slices
    for (int idx = tid; idx < TK * 16; idx += 256) {
        const int j = idx >> 4, d4 = (idx & 15) << 2;
        const float* p = qkvP + base + (size_t)j * 1536 + 512 + d4;
        const float4 v0 = *(const float4*)p;
        const float4 v1 = *(const float4*)(p + pstride);
        const float4 v2 = *(const float4*)(p + 2 * pstride);
        const float4 v3 = *(const float4*)(p + 3 * pstride);
        float4 v;
        v.x = v0.x + v1.x + v2.x + v3.x; v.y = v0.y + v1.y + v2.y + v3.y;
        v.z = v0.z + v1.z + v2.z + v3.z; v.w = v0.w + v1.w + v2.w + v3.w;
        *(float4*)&KVs[j][d4] = v;
    }
    // stage Q tile (16 rows)
    {
        const int idx = tid;  // 256 == 16*16 exactly
        const int j = idx >> 4, d4 = (idx & 15) << 2;
        const float* p = qkvP + base + (size_t)(q0 + j) * 1536 + d4;
        const float4 v0 = *(const float4*)p;
        const float4 v1 = *(const float4*)(p + pstride);
        const float4 v2 = *(const float4*)(p + 2 * pstride);
        const float4 v3 = *(const float4*)(p + 3 * pstride);
        float4 v;
        v.x = v0.x + v1.x + v2.x + v3.x; v.y = v0.y + v1.y + v2.y + v3.y;
        v.z = v0.z + v1.z + v2.z + v3.z; v.w = v0.w + v1.w + v2.w + v3.w;
        *(float4*)&Qs[j][d4] = v;
    }
    __syncthreads();

    const int qpos = q0 + ty;
    constexpr int NJ = TK >> 4;
    float s[NJ];
#pragma unroll
    for (int jj = 0; jj < NJ; jj++) {
        const int j = tx + (jj << 4);
        float acc = 0.f;
#pragma unroll
        for (int d = 0; d < 64; d += 4) {
            const float4 qv = *(const float4*)(&Qs[ty][d]);
            const float4 kv = *(const float4*)(&KVs[j][d]);
            acc += qv.x * kv.x + qv.y * kv.y + qv.z * kv.z + qv.w * kv.w;
        }
        acc *= 0.125f;  // 1/sqrt(64)
        if (MODE == 1 && j > qpos) acc += -1e9f;
        if (MODE == 2 && j >= cur) acc += -1e9f;
        s[jj] = acc;
    }
    // wave-parallel softmax across the 16-lane tx group (same q row)
    float m = s[0];
#pragma unroll
    for (int jj = 1; jj < NJ; jj++) m = fmaxf(m, s[jj]);
#pragma unroll
    for (int o = 8; o >= 1; o >>= 1) m = fmaxf(m, __shfl_xor(m, o, 16));
    float sum = 0.f;
#pragma unroll
    for (int jj = 0; jj < NJ; jj++) {
        const float e = expf(s[jj] - m);
        s[jj] = e;
        sum += e;
    }
#pragma unroll
    for (int o = 8; o >= 1; o >>= 1) sum += __shfl_xor(sum, o, 16);
    const float inv = 1.f / sum;

    __syncthreads();  // all K reads done; safe to overwrite KVs with V

    // stage V (sum 4 slices) into KVs; write P
    for (int idx = tid; idx < TK * 16; idx += 256) {
        const int j = idx >> 4, d4 = (idx & 15) << 2;
        const float* p = qkvP + base + (size_t)j * 1536 + 1024 + d4;
        const float4 v0 = *(const float4*)p;
        const float4 v1 = *(const float4*)(p + pstride);
        const float4 v2 = *(const float4*)(p + 2 * pstride);
        const float4 v3 = *(const float4*)(p + 3 * pstride);
        float4 v;
        v.x = v0.x + v1.x + v2.x + v3.x; v.y = v0.y + v1.y + v2.y + v3.y;
        v.z = v0.z + v1.z + v2.z + v3.z; v.w = v0.w + v1.w + v2.w + v3.w;
        *(float4*)&KVs[j][d4] = v;
    }
#pragma unroll
    for (int jj = 0; jj < NJ; jj++) Ps[ty][tx + (jj << 4)] = s[jj] * inv;
    __syncthreads();

    // O[ty][tx*4..+3] = sum_j P[ty][j] * V[j][tx*4..+3]   (all LDS)
    float4 o4 = make_float4(0.f, 0.f, 0.f, 0.f);
#pragma unroll 4
    for (int j = 0; j < TK; j++) {
        const float p = Ps[ty][j];
        const float4 v = *(const float4*)(&KVs[j][tx << 2]);
        o4.x = fmaf(p, v.x, o4.x); o4.y = fmaf(p, v.y, o4.y);
        o4.z = fmaf(p, v.z, o4.z); o4.w = fmaf(p, v.w, o4.w);
    }
    *(float4*)(out + (size_t)(b * T + q0 + ty) * EE + h * 64 + (tx << 2)) = o4;
}

// ---------------------------------------------------------------------------
// out[r] = LN(X[r] + sum4(SaP[r])) * g + b   (one wave per 512-wide row)
// ---------------------------------------------------------------------------
__global__ __launch_bounds__(64) void resln_kernel(
    const float* __restrict__ X, const float* __restrict__ SaP, size_t pstride,
    const float* __restrict__ g, const float* __restrict__ bta,
    float* __restrict__ out)
{
    const int r = blockIdx.x;
    const int l = threadIdx.x;
    const float* xr = X + (size_t)r * EE;
    const float* sr = SaP + (size_t)r * EE;
    float4 v[2];
    float sum = 0.f;
#pragma unroll
    for (int p = 0; p < 2; p++) {
        const int o = p * 256 + l * 4;
        const float4 a = *(const float4*)(xr + o);
        const float4 c0 = *(const float4*)(sr + o);
        const float4 c1 = *(const float4*)(sr + pstride + o);
        const float4 c2 = *(const float4*)(sr + 2 * pstride + o);
        const float4 c3 = *(const float4*)(sr + 3 * pstride + o);
        v[p] = make_float4(a.x + c0.x + c1.x + c2.x + c3.x,
                           a.y + c0.y + c1.y + c2.y + c3.y,
                           a.z + c0.z + c1.z + c2.z + c3.z,
                           a.w + c0.w + c1.w + c2.w + c3.w);
        sum += v[p].x + v[p].y + v[p].z + v[p].w;
    }
#pragma unroll
    for (int o = 32; o >= 1; o >>= 1) sum += __shfl_xor(sum, o, 64);
    const float mean = sum * (1.f / EE);
    float vs = 0.f;
#pragma unroll
    for (int p = 0; p < 2; p++) {
        const float dx = v[p].x - mean, dy = v[p].y - mean;
        const float dz = v[p].z - mean, dw = v[p].w - mean;
        vs += dx * dx + dy * dy + dz * dz + dw * dw;
    }
#pragma unroll
    for (int o = 32; o >= 1; o >>= 1) vs += __shfl_xor(vs, o, 64);
    const float rstd = 1.f / sqrtf(vs * (1.f / EE) + 1e-5f);
#pragma unroll
    for (int p = 0; p < 2; p++) {
        const int o = p * 256 + l * 4;
        const float4 gv = *(const float4*)(g + o);
        const float4 bv = *(const float4*)(bta + o);
        float4 ov;
        ov.x = (v[p].x - mean) * rstd * gv.x + bv.x;
        ov.y = (v[p].y - mean) * rstd * gv.y + bv.y;
        ov.z = (v[p].z - mean) * rstd * gv.z + bv.z;
        ov.w = (v[p].w - mean) * rstd * gv.w + bv.w;
        *(float4*)(out + (size_t)r * EE + o) = ov;
    }
}

// src = LN(embedding[seq] + pos_emb[s]) — one wave per (b,s) row
__global__ __launch_bounds__(64) void embed_ln_kernel(
    const int* __restrict__ seq, const float* __restrict__ emb,
    const float* __restrict__ pemb, const float* __restrict__ g,
    const float* __restrict__ bta, float* __restrict__ out)
{
    const int r = blockIdx.x;           // b*S + s
    const int s = r & (SS - 1);
    const int l = threadIdx.x;
    const int tok = seq[r];
    const float* er = emb + (size_t)tok * EE;
    const float* pr = pemb + (size_t)s * EE;
    float4 v[2];
    float sum = 0.f;
#pragma unroll
    for (int p = 0; p < 2; p++) {
        const int o = p * 256 + l * 4;
        const float4 a = *(const float4*)(er + o);
        const float4 c = *(const float4*)(pr + o);
        v[p] = make_float4(a.x + c.x, a.y + c.y, a.z + c.z, a.w + c.w);
        sum += v[p].x + v[p].y + v[p].z + v[p].w;
    }
#pragma unroll
    for (int o = 32; o >= 1; o >>= 1) sum += __shfl_xor(sum, o, 64);
    const float mean = sum * (1.f / EE);
    float vs = 0.f;
#pragma unroll
    for (int p = 0; p < 2; p++) {
        const float dx = v[p].x - mean, dy = v[p].y - mean;
        const float dz = v[p].z - mean, dw = v[p].w - mean;
        vs += dx * dx + dy * dy + dz * dz + dw * dw;
    }
#pragma unroll
    for (int o = 32; o >= 1; o >>= 1) vs += __shfl_xor(vs, o, 64);
    const float rstd = 1.f / sqrtf(vs * (1.f / EE) + 1e-5f);
#pragma unroll
    for (int p = 0; p < 2; p++) {
        const int o = p * 256 + l * 4;
        const float4 gv = *(const float4*)(g + o);
        const float4 bv = *(const float4*)(bta + o);
        float4 ov;
        ov.x = (v[p].x - mean) * rstd * gv.x + bv.x;
        ov.y = (v[p].y - mean) * rstd * gv.y + bv.y;
        ov.z = (v[p].z - mean) * rstd * gv.z + bv.z;
        ov.w = (v[p].w - mean) * rstd * gv.w + bv.w;
        *(float4*)(out + (size_t)r * EE + o) = ov;
    }
}

// buf[:, :S] = xe ; buf[:, S:] = 0
__global__ void bufinit_kernel(const float* __restrict__ xe, float* __restrict__ buf)
{
    const int idx = blockIdx.x * 256 + threadIdx.x;
    if (idx < BB * TT * EE) {
        const int e = idx & (EE - 1);
        const int t = (idx >> 9) % TT;
        const int b = idx / (EE * TT);
        buf[idx] = (t < SS) ? xe[((size_t)b * SS + t) * EE + e] : 0.f;
    }
}

// logits[b][col] = dot(tgt[b, cur-1, :], fo_w[col, :]) + fo_b[col]
__global__ __launch_bounds__(256) void logits_kernel(
    const float* __restrict__ tgt, const float* __restrict__ foW,
    const float* __restrict__ fob, float* __restrict__ logits, int cur)
{
    __shared__ float last_s[BB][EE];
    const int tid = threadIdx.x;
    for (int idx = tid; idx < BB * EE; idx += 256) {
        const int b = idx >> 9, e = idx & (EE - 1);
        last_s[b][e] = tgt[((size_t)b * TT + (cur - 1)) * EE + e];
    }
    __syncthreads();
    const int w = tid >> 6, l = tid & 63;
    const int col = blockIdx.x * 4 + w;
    float a0 = 0.f, a1 = 0.f, a2 = 0.f, a3 = 0.f;
    const float* wr = foW + (size_t)col * EE;
#pragma unroll
    for (int p = 0; p < 2; p++) {
        const int o = p * 256 + l * 4;
        const float4 wv = *(const float4*)(wr + o);
        const float4 l0 = *(const float4*)(&last_s[0][o]);
        const float4 l1 = *(const float4*)(&last_s[1][o]);
        const float4 l2 = *(const float4*)(&last_s[2][o]);
        const float4 l3 = *(const float4*)(&last_s[3][o]);
        a0 += wv.x * l0.x + wv.y * l0.y + wv.z * l0.z + wv.w * l0.w;
        a1 += wv.x * l1.x + wv.y * l1.y + wv.z * l1.z + wv.w * l1.w;
        a2 += wv.x * l2.x + wv.y * l2.y + wv.z * l2.z + wv.w * l2.w;
        a3 += wv.x * l3.x + wv.y * l3.y + wv.z * l3.z + wv.w * l3.w;
    }
#pragma unroll
    for (int o = 32; o >= 1; o >>= 1) {
        a0 += __shfl_xor(a0, o, 64); a1 += __shfl_xor(a1, o, 64);
        a2 += __shfl_xor(a2, o, 64); a3 += __shfl_xor(a3, o, 64);
    }
    if (l == 0) {
        const float bb = fob[col];
        logits[(size_t)0 * VV + col] = a0 + bb;
        logits[(size_t)1 * VV + col] = a1 + bb;
        logits[(size_t)2 * VV + col] = a2 + bb;
        logits[(size_t)3 * VV + col] = a3 + bb;
    }
}

// argmax over V (first-index tie-break), write token, append embedding[tok]
__global__ __launch_bounds__(256) void argmax_kernel(
    const float* __restrict__ logits, const float* __restrict__ emb,
    float* __restrict__ buf, int* __restrict__ out_tok, int cur, int step)
{
    __shared__ float sv[256];
    __shared__ int si[256];
    const int b = blockIdx.x;
    const int tid = threadIdx.x;
    float best = -3.4e38f;
    int bi = 0x7fffffff;
    for (int v = tid; v < VV; v += 256) {
        const float x = logits[(size_t)b * VV + v];
        if (x > best) { best = x; bi = v; }
    }
    sv[tid] = best; si[tid] = bi;
    __syncthreads();
    for (int s = 128; s > 0; s >>= 1) {
        if (tid < s) {
            const float xo = sv[tid + s]; const int io = si[tid + s];
            if (xo > sv[tid] || (xo == sv[tid] && io < si[tid])) { sv[tid] = xo; si[tid] = io; }
        }
        __syncthreads();
    }
    const int tok = si[0];
    if (tid == 0) out_tok[b * MM + step] = tok;
    for (int e = tid; e < EE; e += 256)
        buf[((size_t)b * TT + cur) * EE + e] = emb[(size_t)tok * EE + e];
}

extern "C" void kernel_launch(void* const* d_in, const int* in_sizes, int n_in,
                              void* d_out, int out_size, void* d_ws, size_t ws_size,
                              hipStream_t stream)
{
    (void)in_sizes; (void)n_in; (void)out_size; (void)ws_size;
    const int*   seq   = (const int*)d_in[0];
    const int*   ptag  = (const int*)d_in[1];
    const int*   ntag  = (const int*)d_in[2];
    const float* emb   = (const float*)d_in[4];
    const float* pemb  = (const float*)d_in[5];
    const float* fcp_w = (const float*)d_in[6];
    const float* fcp_b = (const float*)d_in[7];
    const float* fcn_w = (const float*)d_in[8];
    const float* fcn_b = (const float*)d_in[9];
    const float* ln_g  = (const float*)d_in[10];
    const float* ln_b  = (const float*)d_in[11];
    const float* asi_w = (const float*)d_in[12];
    const float* asi_b = (const float*)d_in[13];
    const float* aso_w = (const float*)d_in[14];
    const float* aso_b = (const float*)d_in[15];
    const float* api_w = (const float*)d_in[16];
    const float* api_b = (const float*)d_in[17];
    const float* apo_w = (const float*)d_in[18];
    const float* apo_b = (const float*)d_in[19];
    const float* ani_w = (const float*)d_in[20];
    const float* ani_b = (const float*)d_in[21];
    const float* ano_w = (const float*)d_in[22];
    const float* ano_b = (const float*)d_in[23];
    const float* dsi_w = (const float*)d_in[24];
    const float* dsi_b = (const float*)d_in[25];
    const float* dso_w = (const float*)d_in[26];
    const float* dso_b = (const float*)d_in[27];
    const float* dci_w = (const float*)d_in[28];
    const float* dci_b = (const float*)d_in[29];
    const float* dco_w = (const float*)d_in[30];
    const float* dco_b = (const float*)d_in[31];
    const float* d1_w  = (const float*)d_in[32];
    const float* d1_b  = (const float*)d_in[33];
    const float* d2_w  = (const float*)d_in[34];
    const float* d2_b  = (const float*)d_in[35];
    const float* dln_g = (const float*)d_in[36];
    const float* dln_b = (const float*)d_in[37];
    const float* fo_w  = (const float*)d_in[38];
    const float* fo_b  = (const float*)d_in[39];
    int* out_tok = (int*)d_out;

    // workspace arena (floats), total ~32.4 MB
    float* ws   = (float*)d_ws;
    float* P    = ws;                    // 4*1179648 = 4718592 (max partial set)
    float* sabP = P + 4718592;           // 4*294912 = 1179648
    float* ffbr = sabP + 1179648;        // 1179648
    float* att  = ffbr + 1179648;        // 294912
    float* tgt  = att + 294912;          // 294912
    float* buf  = tgt + 294912;          // 294912
    float* lg   = buf + 294912;          // 128000
    // encoder-phase aliases (sabP/ffbr region is free during encoder)
    float* src = sabP;                   // 262144
    float* xe  = sabP + 262144;          // 262144
    float* pf  = sabP + 524288;          // 262144
    float* nf  = sabP + 786432;          // 262144 (ends 1048576 < 1179648)

    const int RS = BB * SS;   // 512 encoder rows
    const int RT = BB * TT;   // 576 decoder rows
    const size_t psE  = (size_t)RS * EE;     // 262144 enc 512-col partial stride
    const size_t psEq = (size_t)RS * 1536;   // 786432 enc qkv partial stride
    const size_t psD  = (size_t)RT * EE;     // 294912 dec 512-col partial stride
    const size_t psDq = (size_t)RT * 1536;   // 884736 dec qkv partial stride
    const size_t psF  = (size_t)RT * FFF;    // 1179648 ffn partial stride

    // ---------------- encoder ----------------
    embed_ln_kernel<<<RS, 64, 0, stream>>>(seq, emb, pemb, ln_g, ln_b, src);
    // pf = embedding[pos_tags] @ fc_pos_w^T + b (gathered A), nf likewise
    gemm_nt<<<dim3(RS / 64, 8, 4), 256, 0, stream>>>(emb, ptag, EE, fcp_w, fcp_b, P, EE, psE, EE, 128);
    reduce4_kernel<<<256, 256, 0, stream>>>(P, psE, pf, 65536, 0);
    gemm_nt<<<dim3(RS / 64, 8, 4), 256, 0, stream>>>(emb, ntag, EE, fcn_w, fcn_b, P, EE, psE, EE, 128);
    reduce4_kernel<<<256, 256, 0, stream>>>(P, psE, nf, 65536, 0);
    // self-attn
    gemm_nt<<<dim3(RS / 64, 24, 4), 256, 0, stream>>>(src, nullptr, EE, asi_w, asi_b, P, 1536, psEq, EE, 128);
    attn_kernel<SS, 0><<<dim3(SS / 16, HH, BB), 256, 0, stream>>>(P, psEq, att, SS, 0);
    gemm_nt<<<dim3(RS / 64, 8, 4), 256, 0, stream>>>(att, nullptr, EE, aso_w, aso_b, P, EE, psE, EE, 128);
    reduce4_kernel<<<256, 256, 0, stream>>>(P, psE, xe, 65536, 0);
    // cross-attn vs pos features (q from xe, kv from pf)
    gemm_nt<<<dim3(RS / 64, 8, 4), 256, 0, stream>>>(xe, nullptr, EE, api_w, api_b, P, 1536, psEq, EE, 128);
    gemm_nt<<<dim3(RS / 64, 16, 4), 256, 0, stream>>>(pf, nullptr, EE, api_w + 512 * EE, api_b + 512, P + 512, 1536, psEq, EE, 128);
    attn_kernel<SS, 0><<<dim3(SS / 16, HH, BB), 256, 0, stream>>>(P, psEq, att, SS, 0);
    gemm_nt<<<dim3(RS / 64, 8, 4), 256, 0, stream>>>(att, nullptr, EE, apo_w, apo_b, P, EE, psE, EE, 128);
    reduce4_kernel<<<256, 256, 0, stream>>>(P, psE, src, 65536, 0);
    // cross-attn vs ner features (q from src, kv from nf)
    gemm_nt<<<dim3(RS / 64, 8, 4), 256, 0, stream>>>(src, nullptr, EE, ani_w, ani_b, P, 1536, psEq, EE, 128);
    gemm_nt<<<dim3(RS / 64, 16, 4), 256, 0, stream>>>(nf, nullptr, EE, ani_w + 512 * EE, ani_b + 512, P + 512, 1536, psEq, EE, 128);
    attn_kernel<SS, 0><<<dim3(SS / 16, HH, BB), 256, 0, stream>>>(P, psEq, att, SS, 0);
    gemm_nt<<<dim3(RS / 64, 8, 4), 256, 0, stream>>>(att, nullptr, EE, ano_w, ano_b, P, EE, psE, EE, 128);
    reduce4_kernel<<<256, 256, 0, stream>>>(P, psE, xe, 65536, 0);
    // buf[:, :S] = xe ; rest zero
    bufinit_kernel<<<(BB * TT * EE + 255) / 256, 256, 0, stream>>>(xe, buf);

    // ---------------- decoder generation loop (host-unrolled, M=16) ----------------
    for (int i = 0; i < MM; i++) {
        const int cur = SS + i;
        for (int l = 0; l < LL; l++) {
            const float* tin = (l == 0) ? buf : tgt;
            // self-attn (causal)
            gemm_nt<<<dim3(RT / 64, 24, 4), 256, 0, stream>>>(tin, nullptr, EE,
                dsi_w + (size_t)l * 1536 * EE, dsi_b + l * 1536, P, 1536, psDq, EE, 128);
            attn_kernel<TT, 1><<<dim3(TT / 16, HH, BB), 256, 0, stream>>>(P, psDq, att, TT, 0);
            gemm_nt<<<dim3(RT / 64, 8, 4), 256, 0, stream>>>(att, nullptr, EE,
                dso_w + (size_t)l * EE * EE, dso_b + l * EE, sabP, EE, psD, EE, 128);
            resln_kernel<<<RT, 64, 0, stream>>>(tin, sabP, psD, dln_g + (l * 3 + 0) * EE, dln_b + (l * 3 + 0) * EE, tgt);
            // cross-attn (q from tgt, kv from buf; keys < cur)
            gemm_nt<<<dim3(RT / 64, 8, 4), 256, 0, stream>>>(tgt, nullptr, EE,
                dci_w + (size_t)l * 1536 * EE, dci_b + l * 1536, P, 1536, psDq, EE, 128);
            gemm_nt<<<dim3(RT / 64, 16, 4), 256, 0, stream>>>(buf, nullptr, EE,
                dci_w + (size_t)l * 1536 * EE + 512 * EE, dci_b + l * 1536 + 512, P + 512, 1536, psDq, EE, 128);
            attn_kernel<TT, 2><<<dim3(TT / 16, HH, BB), 256, 0, stream>>>(P, psDq, att, TT, cur);
            gemm_nt<<<dim3(RT / 64, 8, 4), 256, 0, stream>>>(att, nullptr, EE,
                dco_w + (size_t)l * EE * EE, dco_b + l * EE, sabP, EE, psD, EE, 128);
            resln_kernel<<<RT, 64, 0, stream>>>(tgt, sabP, psD, dln_g + (l * 3 + 1) * EE, dln_b + (l * 3 + 1) * EE, tgt);
            // FFN: ffbP = tgt @ W1^T (+b1 in slice0) ; ffbr = relu(sum4) ; sabP = ffbr @ W2^T
            gemm_nt<<<dim3(RT / 64, 32, 4), 256, 0, stream>>>(tgt, nullptr, EE,
                d1_w + (size_t)l * FFF * EE, d1_b + l * FFF, P, FFF, psF, EE, 128);
            reduce4_kernel<<<1152, 256, 0, stream>>>(P, psF, ffbr, 294912, 1);
            gemm_nt<<<dim3(RT / 64, 8, 4), 256, 0, stream>>>(ffbr, nullptr, FFF,
                d2_w + (size_t)l * EE * FFF, d2_b + l * EE, sabP, EE, psD, FFF, 512);
            resln_kernel<<<RT, 64, 0, stream>>>(tgt, sabP, psD, dln_g + (l * 3 + 2) * EE, dln_b + (l * 3 + 2) * EE, tgt);
        }
        logits_kernel<<<VV / 4, 256, 0, stream>>>(tgt, fo_w, fo_b, lg, cur);
        argmax_kernel<<<BB, 256, 0, stream>>>(lg, emb, buf, out_tok, cur, i);
    }
}

// Round 5
// 5120.981 us; speedup vs baseline: 2.2790x; 1.3359x over previous
//
#include <hip/hip_runtime.h>

// Problem constants: B=4,S=128,E=512,H=8,Dh=64,V=32000,M=16,T=144,L=2,FF=2048
#define BB 4
#define SS 128
#define EE 512
#define HH 8
#define VV 32000
#define MM 16
#define TT 144
#define LL 2
#define FFF 2048

typedef short short8 __attribute__((ext_vector_type(8)));
typedef float f32x4 __attribute__((ext_vector_type(4)));

// ---------------------------------------------------------------------------
// f32 -> bf16 hi/lo split (RNE), error-compensated: x ~= hi + lo, |err|~2^-17|x|
// ---------------------------------------------------------------------------
__device__ __forceinline__ ushort bf16_rne(float x) {
    uint u = __float_as_uint(x);
    return (ushort)((u + 0x7FFF + ((u >> 16) & 1)) >> 16);
}
__device__ __forceinline__ void split2(float x, ushort& hs, ushort& ls) {
    hs = bf16_rne(x);
    const float hf = __uint_as_float((uint)hs << 16);
    ls = bf16_rne(x - hf);
}

// Pre-split a weight tensor into hi/lo bf16 planes (same element indexing).
__global__ __launch_bounds__(256) void split_kernel(
    const float* __restrict__ src, ushort* __restrict__ hi,
    ushort* __restrict__ lo, int n4)
{
    int i = blockIdx.x * 256 + threadIdx.x;
    const int stride = gridDim.x * 256;
    for (; i < n4; i += stride) {
        const float4 v = ((const float4*)src)[i];
        ushort h0, h1, h2, h3, l0, l1, l2, l3;
        split2(v.x, h0, l0); split2(v.y, h1, l1);
        split2(v.z, h2, l2); split2(v.w, h3, l3);
        ((ushort4*)hi)[i] = make_ushort4(h0, h1, h2, h3);
        ((ushort4*)lo)[i] = make_ushort4(l0, l1, l2, l3);
    }
}

// ---------------------------------------------------------------------------
// bf16x3 MFMA split-K GEMM: Cp[z] = A[M,Kslice_z] @ W[N,Kslice_z]^T (+bias z==0)
// A is f32 (converted to hi/lo in-kernel, amortized by 64x64 tile reuse).
// W pre-split into hi/lo ushort planes [N][K].  a*b = ah*bh + ah*bl + al*bh.
// Tile 64x64, K-step 64, 256 thr = 4 waves; wave w owns rows 16w..16w+15.
// mfma_f32_16x16x32_bf16: A row=l&15,k=(l>>4)*8+j ; D col=l&15,row=(l>>4)*4+r.
// ---------------------------------------------------------------------------
__global__ __launch_bounds__(256, 2) void gemm3_nt(
    const float* __restrict__ A, int lda,
    const ushort* __restrict__ Whi, const ushort* __restrict__ Wlo,
    const float* __restrict__ bias,
    float* __restrict__ C, int ldc, size_t pstride, int K, int Kslice)
{
    __shared__ ushort Ah[64][72], Al[64][72], Wh[64][72], Wl[64][72];
    const int tid = threadIdx.x;
    const int l = tid & 63, w = tid >> 6;          // lane, wave
    const int m0 = blockIdx.x * 64, n0 = blockIdx.y * 64;
    const int z = blockIdx.z;
    const int srow = tid >> 2;                     // staging row 0..63
    const int skb = (tid & 3) << 4;                // staging k-base 0,16,32,48
    const float* Arow = A + (size_t)(m0 + srow) * lda;
    const ushort* WhRow = Whi + (size_t)(n0 + srow) * K;
    const ushort* WlRow = Wlo + (size_t)(n0 + srow) * K;

    f32x4 acc[4];
#pragma unroll
    for (int ns = 0; ns < 4; ns++) acc[ns] = (f32x4)0.f;

    const int kbeg = z * Kslice, kend = kbeg + Kslice;
    for (int k0 = kbeg; k0 < kend; k0 += 64) {
        // ---- load & convert (before barrier: overlaps prior compute) ----
        float av[16];
#pragma unroll
        for (int q = 0; q < 4; q++) {
            const float4 v = *(const float4*)(Arow + k0 + skb + q * 4);
            av[q * 4 + 0] = v.x; av[q * 4 + 1] = v.y;
            av[q * 4 + 2] = v.z; av[q * 4 + 3] = v.w;
        }
        uint ahp[8], alp[8];
#pragma unroll
        for (int q = 0; q < 8; q++) {
            ushort h0, h1, l0_, l1_;
            split2(av[2 * q], h0, l0_);
            split2(av[2 * q + 1], h1, l1_);
            ahp[q] = (uint)h0 | ((uint)h1 << 16);
            alp[q] = (uint)l0_ | ((uint)l1_ << 16);
        }
        const uint4 wh0 = *(const uint4*)(WhRow + k0 + skb);
        const uint4 wh1 = *(const uint4*)(WhRow + k0 + skb + 8);
        const uint4 wl0 = *(const uint4*)(WlRow + k0 + skb);
        const uint4 wl1 = *(const uint4*)(WlRow + k0 + skb + 8);
        __syncthreads();
        *(uint4*)&Ah[srow][skb] = make_uint4(ahp[0], ahp[1], ahp[2], ahp[3]);
        *(uint4*)&Ah[srow][skb + 8] = make_uint4(ahp[4], ahp[5], ahp[6], ahp[7]);
        *(uint4*)&Al[srow][skb] = make_uint4(alp[0], alp[1], alp[2], alp[3]);
        *(uint4*)&Al[srow][skb + 8] = make_uint4(alp[4], alp[5], alp[6], alp[7]);
        *(uint4*)&Wh[srow][skb] = wh0;
        *(uint4*)&Wh[srow][skb + 8] = wh1;
        *(uint4*)&Wl[srow][skb] = wl0;
        *(uint4*)&Wl[srow][skb + 8] = wl1;
        __syncthreads();
        // ---- compute: 2 k-subtiles x 4 n-subtiles x 3 mfma ----
        const int fr = l & 15, fg = (l >> 4) << 3;  // frag row / k-group*8
#pragma unroll
        for (int ks = 0; ks < 2; ks++) {
            const short8 a_h = *(const short8*)&Ah[16 * w + fr][32 * ks + fg];
            const short8 a_l = *(const short8*)&Al[16 * w + fr][32 * ks + fg];
#pragma unroll
            for (int ns = 0; ns < 4; ns++) {
                const short8 b_h = *(const short8*)&Wh[16 * ns + fr][32 * ks + fg];
                const short8 b_l = *(const short8*)&Wl[16 * ns + fr][32 * ks + fg];
                acc[ns] = __builtin_amdgcn_mfma_f32_16x16x32_bf16(a_h, b_h, acc[ns], 0, 0, 0);
                acc[ns] = __builtin_amdgcn_mfma_f32_16x16x32_bf16(a_h, b_l, acc[ns], 0, 0, 0);
                acc[ns] = __builtin_amdgcn_mfma_f32_16x16x32_bf16(a_l, b_h, acc[ns], 0, 0, 0);
            }
        }
    }

    // ---- epilogue: D col=l&15, row=(l>>4)*4+r ----
    float* Cz = C + z * pstride;
    const int fr = l & 15, r4 = (l >> 4) << 2;
#pragma unroll
    for (int ns = 0; ns < 4; ns++) {
        const int col = n0 + 16 * ns + fr;
        const float bc = (bias && z == 0) ? bias[col] : 0.f;
#pragma unroll
        for (int r = 0; r < 4; r++) {
            const int row = m0 + 16 * w + r4 + r;
            Cz[(size_t)row * ldc + col] = acc[ns][r] + bc;
        }
    }
}

// ---------------------------------------------------------------------------
// f32 split-K tiled GEMM (encoder only): Cp[z] = A @ W^T (+bias z==0)
// ---------------------------------------------------------------------------
__global__ __launch_bounds__(256, 2) void gemm_nt(
    const float* __restrict__ A, const int* __restrict__ Aidx, int lda,
    const float* __restrict__ W, const float* __restrict__ bias,
    float* __restrict__ C, int ldc, size_t pstride, int K, int Kslice)
{
    __shared__ float As[16][68];
    __shared__ float Ws[16][68];
    const int tid = threadIdx.x;
    const int tx = tid & 15, ty = tid >> 4;
    const int m0 = blockIdx.x * 64, n0 = blockIdx.y * 64;
    const int z = blockIdx.z;
    const int lrow = tid >> 2;
    const int lk = (tid & 3) << 2;
    const float* Arow;
    if (Aidx) Arow = A + (size_t)Aidx[m0 + lrow] * lda;
    else      Arow = A + (size_t)(m0 + lrow) * lda;
    const float* Wrow = W + (size_t)(n0 + lrow) * K;

    float acc[4][4];
#pragma unroll
    for (int i = 0; i < 4; i++)
#pragma unroll
        for (int j = 0; j < 4; j++) acc[i][j] = 0.f;

    const int kbeg = z * Kslice, kend = kbeg + Kslice;
    for (int k0 = kbeg; k0 < kend; k0 += 16) {
        const float4 av = *(const float4*)(Arow + k0 + lk);
        const float4 wv = *(const float4*)(Wrow + k0 + lk);
        __syncthreads();
        As[lk + 0][lrow] = av.x; As[lk + 1][lrow] = av.y;
        As[lk + 2][lrow] = av.z; As[lk + 3][lrow] = av.w;
        Ws[lk + 0][lrow] = wv.x; Ws[lk + 1][lrow] = wv.y;
        Ws[lk + 2][lrow] = wv.z; Ws[lk + 3][lrow] = wv.w;
        __syncthreads();
#pragma unroll
        for (int k = 0; k < 16; k++) {
            const float4 a = *(const float4*)(&As[k][ty << 2]);
            const float4 bq = *(const float4*)(&Ws[k][tx << 2]);
            acc[0][0] += a.x * bq.x; acc[0][1] += a.x * bq.y; acc[0][2] += a.x * bq.z; acc[0][3] += a.x * bq.w;
            acc[1][0] += a.y * bq.x; acc[1][1] += a.y * bq.y; acc[1][2] += a.y * bq.z; acc[1][3] += a.y * bq.w;
            acc[2][0] += a.z * bq.x; acc[2][1] += a.z * bq.y; acc[2][2] += a.z * bq.z; acc[2][3] += a.z * bq.w;
            acc[3][0] += a.w * bq.x; acc[3][1] += a.w * bq.y; acc[3][2] += a.w * bq.z; acc[3][3] += a.w * bq.w;
        }
    }

    float4 bv = make_float4(0.f, 0.f, 0.f, 0.f);
    if (bias && z == 0) bv = *(const float4*)(bias + n0 + (tx << 2));
    float* Cz = C + z * pstride;
#pragma unroll
    for (int i = 0; i < 4; i++) {
        const int r = m0 + (ty << 2) + i;
        float4 o;
        o.x = acc[i][0] + bv.x; o.y = acc[i][1] + bv.y;
        o.z = acc[i][2] + bv.z; o.w = acc[i][3] + bv.w;
        *(float4*)(Cz + (size_t)r * ldc + n0 + (tx << 2)) = o;
    }
}

// out[i] = maybe_relu(sum_z Pz[i])  (float4 granularity)
__global__ __launch_bounds__(256) void reduce_kernel(
    const float* __restrict__ P, size_t pstride,
    float* __restrict__ out, int n4, int relu, int znum)
{
    int i = blockIdx.x * 256 + threadIdx.x;
    const int stride = gridDim.x * 256;
    for (; i < n4; i += stride) {
        float4 o = ((const float4*)P)[i];
        for (int zz = 1; zz < znum; zz++) {
            const float4 b = ((const float4*)(P + zz * pstride))[i];
            o.x += b.x; o.y += b.y; o.z += b.z; o.w += b.w;
        }
        if (relu) {
            o.x = fmaxf(o.x, 0.f); o.y = fmaxf(o.y, 0.f);
            o.z = fmaxf(o.z, 0.f); o.w = fmaxf(o.w, 0.f);
        }
        ((float4*)out)[i] = o;
    }
}

// ---------------------------------------------------------------------------
// Attention over split-K qkv partials (sums NZ slices at stage time).
// qkvP per slice: [B,T,1536] (q 0..511, k 512..1023, v 1024..1535).
// Block = (qtile16, h, b).  MODE: 0 none, 1 causal, 2 keylimit.
// ---------------------------------------------------------------------------
template<int TK, int MODE, int NZ>
__global__ __launch_bounds__(256) void attn_kernel(
    const float* __restrict__ qkvP, size_t pstride, float* __restrict__ out,
    int T, int cur)
{
    __shared__ float KVs[TK][68];
    __shared__ float Qs[16][68];
    __shared__ float Ps[16][TK + 4];
    const int tid = threadIdx.x;
    const int tx = tid & 15, ty = tid >> 4;
    const int q0 = blockIdx.x * 16;
    const int h = blockIdx.y, b = blockIdx.z;
    const size_t base = (size_t)b * T * 1536 + h * 64;

    for (int idx = tid; idx < TK * 16; idx += 256) {
        const int j = idx >> 4, d4 = (idx & 15) << 2;
        const float* p = qkvP + base + (size_t)j * 1536 + 512 + d4;
        float4 v = *(const float4*)p;
#pragma unroll
        for (int zz = 1; zz < NZ; zz++) {
            const float4 u = *(const float4*)(p + zz * pstride);
            v.x += u.x; v.y += u.y; v.z += u.z; v.w += u.w;
        }
        *(float4*)&KVs[j][d4] = v;
    }
    {
        const int j = tid >> 4, d4 = (tid & 15) << 2;
        const float* p = qkvP + base + (size_t)(q0 + j) * 1536 + d4;
        float4 v = *(const float4*)p;
#pragma unroll
        for (int zz = 1; zz < NZ; zz++) {
            const float4 u = *(const float4*)(p + zz * pstride);
            v.x += u.x; v.y += u.y; v.z += u.z; v.w += u.w;
        }
        *(float4*)&Qs[j][d4] = v;
    }
    __syncthreads();

    const int qpos = q0 + ty;
    constexpr int NJ = TK >> 4;
    float s[NJ];
#pragma unroll
    for (int jj = 0; jj < NJ; jj++) {
        const int j = tx + (jj << 4);
        float acc = 0.f;
#pragma unroll
        for (int d = 0; d < 64; d += 4) {
            const float4 qv = *(const float4*)(&Qs[ty][d]);
            const float4 kv = *(const float4*)(&KVs[j][d]);
            acc += qv.x * kv.x + qv.y * kv.y + qv.z * kv.z + qv.w * kv.w;
        }
        acc *= 0.125f;
        if (MODE == 1 && j > qpos) acc += -1e9f;
        if (MODE == 2 && j >= cur) acc += -1e9f;
        s[jj] = acc;
    }
    float m = s[0];
#pragma unroll
    for (int jj = 1; jj < NJ; jj++) m = fmaxf(m, s[jj]);
#pragma unroll
    for (int o = 8; o >= 1; o >>= 1) m = fmaxf(m, __shfl_xor(m, o, 16));
    float sum = 0.f;
#pragma unroll
    for (int jj = 0; jj < NJ; jj++) {
        const float e = expf(s[jj] - m);
        s[jj] = e;
        sum += e;
    }
#pragma unroll
    for (int o = 8; o >= 1; o >>= 1) sum += __shfl_xor(sum, o, 16);
    const float inv = 1.f / sum;

    __syncthreads();  // all K reads done; reuse KVs for V

    for (int idx = tid; idx < TK * 16; idx += 256) {
        const int j = idx >> 4, d4 = (idx & 15) << 2;
        const float* p = qkvP + base + (size_t)j * 1536 + 1024 + d4;
        float4 v = *(const float4*)p;
#pragma unroll
        for (int zz = 1; zz < NZ; zz++) {
            const float4 u = *(const float4*)(p + zz * pstride);
            v.x += u.x; v.y += u.y; v.z += u.z; v.w += u.w;
        }
        *(float4*)&KVs[j][d4] = v;
    }
#pragma unroll
    for (int jj = 0; jj < NJ; jj++) Ps[ty][tx + (jj << 4)] = s[jj] * inv;
    __syncthreads();

    float4 o4 = make_float4(0.f, 0.f, 0.f, 0.f);
#pragma unroll 4
    for (int j = 0; j < TK; j++) {
        const float p = Ps[ty][j];
        const float4 v = *(const float4*)(&KVs[j][tx << 2]);
        o4.x = fmaf(p, v.x, o4.x); o4.y = fmaf(p, v.y, o4.y);
        o4.z = fmaf(p, v.z, o4.z); o4.w = fmaf(p, v.w, o4.w);
    }
    *(float4*)(out + (size_t)(b * T + q0 + ty) * EE + h * 64 + (tx << 2)) = o4;
}

// out[r] = LN(X[r] + sum4(SaP[r])) * g + b
__global__ __launch_bounds__(64) void resln_kernel(
    const float* __restrict__ X, const float* __restrict__ SaP, size_t pstride,
    const float* __restrict__ g, const float* __restrict__ bta,
    float* __restrict__ out)
{
    const int r = blockIdx.x;
    const int l = threadIdx.x;
    const float* xr = X + (size_t)r * EE;
    const float* sr = SaP + (size_t)r * EE;
    float4 v[2];
    float sum = 0.f;
#pragma unroll
    for (int p = 0; p < 2; p++) {
        const int o = p * 256 + l * 4;
        const float4 a = *(const float4*)(xr + o);
        const float4 c0 = *(const float4*)(sr + o);
        const float4 c1 = *(const float4*)(sr + pstride + o);
        const float4 c2 = *(const float4*)(sr + 2 * pstride + o);
        const float4 c3 = *(const float4*)(sr + 3 * pstride + o);
        v[p] = make_float4(a.x + c0.x + c1.x + c2.x + c3.x,
                           a.y + c0.y + c1.y + c2.y + c3.y,
                           a.z + c0.z + c1.z + c2.z + c3.z,
                           a.w + c0.w + c1.w + c2.w + c3.w);
        sum += v[p].x + v[p].y + v[p].z + v[p].w;
    }
#pragma unroll
    for (int o = 32; o >= 1; o >>= 1) sum += __shfl_xor(sum, o, 64);
    const float mean = sum * (1.f / EE);
    float vs = 0.f;
#pragma unroll
    for (int p = 0; p < 2; p++) {
        const float dx = v[p].x - mean, dy = v[p].y - mean;
        const float dz = v[p].z - mean, dw = v[p].w - mean;
        vs += dx * dx + dy * dy + dz * dz + dw * dw;
    }
#pragma unroll
    for (int o = 32; o >= 1; o >>= 1) vs += __shfl_xor(vs, o, 64);
    const float rstd = 1.f / sqrtf(vs * (1.f / EE) + 1e-5f);
#pragma unroll
    for (int p = 0; p < 2; p++) {
        const int o = p * 256 + l * 4;
        const float4 gv = *(const float4*)(g + o);
        const float4 bv = *(const float4*)(bta + o);
        float4 ov;
        ov.x = (v[p].x - mean) * rstd * gv.x + bv.x;
        ov.y = (v[p].y - mean) * rstd * gv.y + bv.y;
        ov.z = (v[p].z - mean) * rstd * gv.z + bv.z;
        ov.w = (v[p].w - mean) * rstd * gv.w + bv.w;
        *(float4*)(out + (size_t)r * EE + o) = ov;
    }
}

// src = LN(embedding[seq] + pos_emb[s])
__global__ __launch_bounds__(64) void embed_ln_kernel(
    const int* __restrict__ seq, const float* __restrict__ emb,
    const float* __restrict__ pemb, const float* __restrict__ g,
    const float* __restrict__ bta, float* __restrict__ out)
{
    const int r = blockIdx.x;
    const int s = r & (SS - 1);
    const int l = threadIdx.x;
    const int tok = seq[r];
    const float* er = emb + (size_t)tok * EE;
    const float* pr = pemb + (size_t)s * EE;
    float4 v[2];
    float sum = 0.f;
#pragma unroll
    for (int p = 0; p < 2; p++) {
        const int o = p * 256 + l * 4;
        const float4 a = *(const float4*)(er + o);
        const float4 c = *(const float4*)(pr + o);
        v[p] = make_float4(a.x + c.x, a.y + c.y, a.z + c.z, a.w + c.w);
        sum += v[p].x + v[p].y + v[p].z + v[p].w;
    }
#pragma unroll
    for (int o = 32; o >= 1; o >>= 1) sum += __shfl_xor(sum, o, 64);
    const float mean = sum * (1.f / EE);
    float vs = 0.f;
#pragma unroll
    for (int p = 0; p < 2; p++) {
        const float dx = v[p].x - mean, dy = v[p].y - mean;
        const float dz = v[p].z - mean, dw = v[p].w - mean;
        vs += dx * dx + dy * dy + dz * dz + dw * dw;
    }
#pragma unroll
    for (int o = 32; o >= 1; o >>= 1) vs += __shfl_xor(vs, o, 64);
    const float rstd = 1.f / sqrtf(vs * (1.f / EE) + 1e-5f);
#pragma unroll
    for (int p = 0; p < 2; p++) {
        const int o = p * 256 + l * 4;
        const float4 gv = *(const float4*)(g + o);
        const float4 bv = *(const float4*)(bta + o);
        float4 ov;
        ov.x = (v[p].x - mean) * rstd * gv.x + bv.x;
        ov.y = (v[p].y - mean) * rstd * gv.y + bv.y;
        ov.z = (v[p].z - mean) * rstd * gv.z + bv.z;
        ov.w = (v[p].w - mean) * rstd * gv.w + bv.w;
        *(float4*)(out + (size_t)r * EE + o) = ov;
    }
}

// buf[:, :S] = xe ; buf[:, S:] = 0
__global__ void bufinit_kernel(const float* __restrict__ xe, float* __restrict__ buf)
{
    const int idx = blockIdx.x * 256 + threadIdx.x;
    if (idx < BB * TT * EE) {
        const int e = idx & (EE - 1);
        const int t = (idx >> 9) % TT;
        const int b = idx / (EE * TT);
        buf[idx] = (t < SS) ? xe[((size_t)b * SS + t) * EE + e] : 0.f;
    }
}

// logits[b][col] = dot(tgt[b, cur-1, :], fo_w[col, :]) + fo_b[col]
__global__ __launch_bounds__(256) void logits_kernel(
    const float* __restrict__ tgt, const float* __restrict__ foW,
    const float* __restrict__ fob, float* __restrict__ logits, int cur)
{
    __shared__ float last_s[BB][EE];
    const int tid = threadIdx.x;
    for (int idx = tid; idx < BB * EE; idx += 256) {
        const int b = idx >> 9, e = idx & (EE - 1);
        last_s[b][e] = tgt[((size_t)b * TT + (cur - 1)) * EE + e];
    }
    __syncthreads();
    const int w = tid >> 6, l = tid & 63;
    const int col = blockIdx.x * 4 + w;
    float a0 = 0.f, a1 = 0.f, a2 = 0.f, a3 = 0.f;
    const float* wr = foW + (size_t)col * EE;
#pragma unroll
    for (int p = 0; p < 2; p++) {
        const int o = p * 256 + l * 4;
        const float4 wv = *(const float4*)(wr + o);
        const float4 l0 = *(const float4*)(&last_s[0][o]);
        const float4 l1 = *(const float4*)(&last_s[1][o]);
        const float4 l2 = *(const float4*)(&last_s[2][o]);
        const float4 l3 = *(const float4*)(&last_s[3][o]);
        a0 += wv.x * l0.x + wv.y * l0.y + wv.z * l0.z + wv.w * l0.w;
        a1 += wv.x * l1.x + wv.y * l1.y + wv.z * l1.z + wv.w * l1.w;
        a2 += wv.x * l2.x + wv.y * l2.y + wv.z * l2.z + wv.w * l2.w;
        a3 += wv.x * l3.x + wv.y * l3.y + wv.z * l3.z + wv.w * l3.w;
    }
#pragma unroll
    for (int o = 32; o >= 1; o >>= 1) {
        a0 += __shfl_xor(a0, o, 64); a1 += __shfl_xor(a1, o, 64);
        a2 += __shfl_xor(a2, o, 64); a3 += __shfl_xor(a3, o, 64);
    }
    if (l == 0) {
        const float bb = fob[col];
        logits[(size_t)0 * VV + col] = a0 + bb;
        logits[(size_t)1 * VV + col] = a1 + bb;
        logits[(size_t)2 * VV + col] = a2 + bb;
        logits[(size_t)3 * VV + col] = a3 + bb;
    }
}

// argmax over V (first-index tie-break), write token, append embedding[tok]
__global__ __launch_bounds__(256) void argmax_kernel(
    const float* __restrict__ logits, const float* __restrict__ emb,
    float* __restrict__ buf, int* __restrict__ out_tok, int cur, int step)
{
    __shared__ float sv[256];
    __shared__ int si[256];
    const int b = blockIdx.x;
    const int tid = threadIdx.x;
    float best = -3.4e38f;
    int bi = 0x7fffffff;
    for (int v = tid; v < VV; v += 256) {
        const float x = logits[(size_t)b * VV + v];
        if (x > best) { best = x; bi = v; }
    }
    sv[tid] = best; si[tid] = bi;
    __syncthreads();
    for (int s = 128; s > 0; s >>= 1) {
        if (tid < s) {
            const float xo = sv[tid + s]; const int io = si[tid + s];
            if (xo > sv[tid] || (xo == sv[tid] && io < si[tid])) { sv[tid] = xo; si[tid] = io; }
        }
        __syncthreads();
    }
    const int tok = si[0];
    if (tid == 0) out_tok[b * MM + step] = tok;
    for (int e = tid; e < EE; e += 256)
        buf[((size_t)b * TT + cur) * EE + e] = emb[(size_t)tok * EE + e];
}

extern "C" void kernel_launch(void* const* d_in, const int* in_sizes, int n_in,
                              void* d_out, int out_size, void* d_ws, size_t ws_size,
                              hipStream_t stream)
{
    (void)in_sizes; (void)n_in; (void)out_size; (void)ws_size;
    const int*   seq   = (const int*)d_in[0];
    const int*   ptag  = (const int*)d_in[1];
    const int*   ntag  = (const int*)d_in[2];
    const float* emb   = (const float*)d_in[4];
    const float* pemb  = (const float*)d_in[5];
    const float* fcp_w = (const float*)d_in[6];
    const float* fcp_b = (const float*)d_in[7];
    const float* fcn_w = (const float*)d_in[8];
    const float* fcn_b = (const float*)d_in[9];
    const float* ln_g  = (const float*)d_in[10];
    const float* ln_b  = (const float*)d_in[11];
    const float* asi_w = (const float*)d_in[12];
    const float* asi_b = (const float*)d_in[13];
    const float* aso_w = (const float*)d_in[14];
    const float* aso_b = (const float*)d_in[15];
    const float* api_w = (const float*)d_in[16];
    const float* api_b = (const float*)d_in[17];
    const float* apo_w = (const float*)d_in[18];
    const float* apo_b = (const float*)d_in[19];
    const float* ani_w = (const float*)d_in[20];
    const float* ani_b = (const float*)d_in[21];
    const float* ano_w = (const float*)d_in[22];
    const float* ano_b = (const float*)d_in[23];
    const float* dsi_w = (const float*)d_in[24];
    const float* dsi_b = (const float*)d_in[25];
    const float* dso_w = (const float*)d_in[26];
    const float* dso_b = (const float*)d_in[27];
    const float* dci_w = (const float*)d_in[28];
    const float* dci_b = (const float*)d_in[29];
    const float* dco_w = (const float*)d_in[30];
    const float* dco_b = (const float*)d_in[31];
    const float* d1_w  = (const float*)d_in[32];
    const float* d1_b  = (const float*)d_in[33];
    const float* d2_w  = (const float*)d_in[34];
    const float* d2_b  = (const float*)d_in[35];
    const float* dln_g = (const float*)d_in[36];
    const float* dln_b = (const float*)d_in[37];
    const float* fo_w  = (const float*)d_in[38];
    const float* fo_b  = (const float*)d_in[39];
    int* out_tok = (int*)d_out;

    // ---- workspace layout ----
    // decoder weight hi/lo planes (8,388,608 elems): 32 MB
    ushort* whi = (ushort*)d_ws;
    ushort* wlo = whi + 8388608;
    // element offsets inside the planes
    const size_t o_dsi = 0;                 // 2*1536*512 = 1,572,864
    const size_t o_dso = 1572864;           // 2*512*512  =   524,288
    const size_t o_dci = 2097152;           // 1,572,864
    const size_t o_dco = 3670016;           //   524,288
    const size_t o_d1  = 4194304;           // 2*2048*512 = 2,097,152
    const size_t o_d2  = 6291456;           // 2,097,152  (end 8,388,608)
    // f32 arena (~26 MB)
    float* arena = (float*)(wlo + 8388608);
    float* P    = arena;                    // 3,145,728 (enc qkv z4 = max)
    float* sabP = P + 3145728;              // 1,179,648 (4 x psD)
    float* ffbr = sabP + 1179648;           // 1,179,648
    float* att  = ffbr + 1179648;           // 294,912
    float* tgt  = att + 294912;             // 294,912
    float* buf  = tgt + 294912;             // 294,912
    float* lg   = buf + 294912;             // 128,000
    // encoder-phase aliases (sabP+ffbr region free during encoder)
    float* src = sabP;
    float* xe  = sabP + 262144;
    float* pf  = sabP + 524288;
    float* nf  = sabP + 786432;

    const int RS = BB * SS;   // 512
    const int RT = BB * TT;   // 576
    const size_t psE  = (size_t)RS * EE;     // 262,144
    const size_t psEq = (size_t)RS * 1536;   // 786,432
    const size_t psD  = (size_t)RT * EE;     // 294,912
    const size_t psDq = (size_t)RT * 1536;   // 884,736
    const size_t psF  = (size_t)RT * FFF;    // 1,179,648

    // ---- one-time per call: split decoder weights into bf16 hi/lo ----
    split_kernel<<<512, 256, 0, stream>>>(dsi_w, whi + o_dsi, wlo + o_dsi, 1572864 / 4);
    split_kernel<<<256, 256, 0, stream>>>(dso_w, whi + o_dso, wlo + o_dso, 524288 / 4);
    split_kernel<<<512, 256, 0, stream>>>(dci_w, whi + o_dci, wlo + o_dci, 1572864 / 4);
    split_kernel<<<256, 256, 0, stream>>>(dco_w, whi + o_dco, wlo + o_dco, 524288 / 4);
    split_kernel<<<512, 256, 0, stream>>>(d1_w, whi + o_d1, wlo + o_d1, 2097152 / 4);
    split_kernel<<<512, 256, 0, stream>>>(d2_w, whi + o_d2, wlo + o_d2, 2097152 / 4);

    // ---------------- encoder (f32 path, runs once) ----------------
    embed_ln_kernel<<<RS, 64, 0, stream>>>(seq, emb, pemb, ln_g, ln_b, src);
    gemm_nt<<<dim3(RS / 64, 8, 4), 256, 0, stream>>>(emb, ptag, EE, fcp_w, fcp_b, P, EE, psE, EE, 128);
    reduce_kernel<<<256, 256, 0, stream>>>(P, psE, pf, 65536, 0, 4);
    gemm_nt<<<dim3(RS / 64, 8, 4), 256, 0, stream>>>(emb, ntag, EE, fcn_w, fcn_b, P, EE, psE, EE, 128);
    reduce_kernel<<<256, 256, 0, stream>>>(P, psE, nf, 65536, 0, 4);
    gemm_nt<<<dim3(RS / 64, 24, 4), 256, 0, stream>>>(src, nullptr, EE, asi_w, asi_b, P, 1536, psEq, EE, 128);
    attn_kernel<SS, 0, 4><<<dim3(SS / 16, HH, BB), 256, 0, stream>>>(P, psEq, att, SS, 0);
    gemm_nt<<<dim3(RS / 64, 8, 4), 256, 0, stream>>>(att, nullptr, EE, aso_w, aso_b, P, EE, psE, EE, 128);
    reduce_kernel<<<256, 256, 0, stream>>>(P, psE, xe, 65536, 0, 4);
    gemm_nt<<<dim3(RS / 64, 8, 4), 256, 0, stream>>>(xe, nullptr, EE, api_w, api_b, P, 1536, psEq, EE, 128);
    gemm_nt<<<dim3(RS / 64, 16, 4), 256, 0, stream>>>(pf, nullptr, EE, api_w + 512 * EE, api_b + 512, P + 512, 1536, psEq, EE, 128);
    attn_kernel<SS, 0, 4><<<dim3(SS / 16, HH, BB), 256, 0, stream>>>(P, psEq, att, SS, 0);
    gemm_nt<<<dim3(RS / 64, 8, 4), 256, 0, stream>>>(att, nullptr, EE, apo_w, apo_b, P, EE, psE, EE, 128);
    reduce_kernel<<<256, 256, 0, stream>>>(P, psE, src, 65536, 0, 4);
    gemm_nt<<<dim3(RS / 64, 8, 4), 256, 0, stream>>>(src, nullptr, EE, ani_w, ani_b, P, 1536, psEq, EE, 128);
    gemm_nt<<<dim3(RS / 64, 16, 4), 256, 0, stream>>>(nf, nullptr, EE, ani_w + 512 * EE, ani_b + 512, P + 512, 1536, psEq, EE, 128);
    attn_kernel<SS, 0, 4><<<dim3(SS / 16, HH, BB), 256, 0, stream>>>(P, psEq, att, SS, 0);
    gemm_nt<<<dim3(RS / 64, 8, 4), 256, 0, stream>>>(att, nullptr, EE, ano_w, ano_b, P, EE, psE, EE, 128);
    reduce_kernel<<<256, 256, 0, stream>>>(P, psE, xe, 65536, 0, 4);
    bufinit_kernel<<<(BB * TT * EE + 255) / 256, 256, 0, stream>>>(xe, buf);

    // ---------------- decoder loop (bf16x3 MFMA GEMMs) ----------------
    for (int i = 0; i < MM; i++) {
        const int cur = SS + i;
        for (int l = 0; l < LL; l++) {
            const float* tin = (l == 0) ? buf : tgt;
            const size_t wl1536 = (size_t)l * 1536 * EE;   // per-layer offsets
            const size_t wl512  = (size_t)l * EE * EE;
            const size_t wlF    = (size_t)l * FFF * EE;
            // self-attn (causal): qkv z=2
            gemm3_nt<<<dim3(RT / 64, 24, 2), 256, 0, stream>>>(tin, EE,
                whi + o_dsi + wl1536, wlo + o_dsi + wl1536, dsi_b + l * 1536, P, 1536, psDq, EE, 256);
            attn_kernel<TT, 1, 2><<<dim3(TT / 16, HH, BB), 256, 0, stream>>>(P, psDq, att, TT, 0);
            gemm3_nt<<<dim3(RT / 64, 8, 4), 256, 0, stream>>>(att, EE,
                whi + o_dso + wl512, wlo + o_dso + wl512, dso_b + l * EE, sabP, EE, psD, EE, 128);
            resln_kernel<<<RT, 64, 0, stream>>>(tin, sabP, psD, dln_g + (l * 3 + 0) * EE, dln_b + (l * 3 + 0) * EE, tgt);
            // cross-attn (q from tgt, kv from buf; keys < cur): z=2
            gemm3_nt<<<dim3(RT / 64, 8, 2), 256, 0, stream>>>(tgt, EE,
                whi + o_dci + wl1536, wlo + o_dci + wl1536, dci_b + l * 1536, P, 1536, psDq, EE, 256);
            gemm3_nt<<<dim3(RT / 64, 16, 2), 256, 0, stream>>>(buf, EE,
                whi + o_dci + wl1536 + 512 * EE, wlo + o_dci + wl1536 + 512 * EE,
                dci_b + l * 1536 + 512, P + 512, 1536, psDq, EE, 256);
            attn_kernel<TT, 2, 2><<<dim3(TT / 16, HH, BB), 256, 0, stream>>>(P, psDq, att, TT, cur);
            gemm3_nt<<<dim3(RT / 64, 8, 4), 256, 0, stream>>>(att, EE,
                whi + o_dco + wl512, wlo + o_dco + wl512, dco_b + l * EE, sabP, EE, psD, EE, 128);
            resln_kernel<<<RT, 64, 0, stream>>>(tgt, sabP, psD, dln_g + (l * 3 + 1) * EE, dln_b + (l * 3 + 1) * EE, tgt);
            // FFN: P(2 slices) = tgt @ W1^T ; ffbr = relu(sum2) ; sabP(4) = ffbr @ W2^T
            gemm3_nt<<<dim3(RT / 64, 32, 2), 256, 0, stream>>>(tgt, EE,
                whi + o_d1 + wlF, wlo + o_d1 + wlF, d1_b + l * FFF, P, FFF, psF, EE, 256);
            reduce_kernel<<<1152, 256, 0, stream>>>(P, psF, ffbr, 294912, 1, 2);
            gemm3_nt<<<dim3(RT / 64, 8, 4), 256, 0, stream>>>(ffbr, FFF,
                whi + o_d2 + wlF, wlo + o_d2 + wlF, d2_b + l * EE, sabP, EE, psD, FFF, 512);
            resln_kernel<<<RT, 64, 0, stream>>>(tgt, sabP, psD, dln_g + (l * 3 + 2) * EE, dln_b + (l * 3 + 2) * EE, tgt);
        }
        logits_kernel<<<VV / 4, 256, 0, stream>>>(tgt, fo_w, fo_b, lg, cur);
        argmax_kernel<<<BB, 256, 0, stream>>>(lg, emb, buf, out_tok, cur, i);
    }
}

// Round 6
// 4714.552 us; speedup vs baseline: 2.4755x; 1.0862x over previous
//
#include <hip/hip_runtime.h>

// Problem constants: B=4,S=128,E=512,H=8,Dh=64,V=32000,M=16,T=144,L=2,FF=2048
#define BB 4
#define SS 128
#define EE 512
#define HH 8
#define VV 32000
#define MM 16
#define TT 144
#define LL 2
#define FFF 2048

typedef short short8 __attribute__((ext_vector_type(8)));
typedef float f32x4 __attribute__((ext_vector_type(4)));

// f32 -> bf16 hi/lo split (RNE): x ~= hi + lo, |err| ~ 2^-17 |x|
__device__ __forceinline__ ushort bf16_rne(float x) {
    uint u = __float_as_uint(x);
    return (ushort)((u + 0x7FFF + ((u >> 16) & 1)) >> 16);
}
__device__ __forceinline__ void split2(float x, ushort& hs, ushort& ls) {
    hs = bf16_rne(x);
    const float hf = __uint_as_float((uint)hs << 16);
    ls = bf16_rne(x - hf);
}
__device__ __forceinline__ void split4(const float4 v, ushort4& h, ushort4& l) {
    split2(v.x, h.x, l.x); split2(v.y, h.y, l.y);
    split2(v.z, h.z, l.z); split2(v.w, h.w, l.w);
}

// Pre-split a weight tensor into hi/lo bf16 planes.
__global__ __launch_bounds__(256) void split_kernel(
    const float* __restrict__ src, ushort* __restrict__ hi,
    ushort* __restrict__ lo, int n4)
{
    int i = blockIdx.x * 256 + threadIdx.x;
    const int stride = gridDim.x * 256;
    for (; i < n4; i += stride) {
        ushort4 h, l;
        split4(((const float4*)src)[i], h, l);
        ((ushort4*)hi)[i] = h;
        ((ushort4*)lo)[i] = l;
    }
}

// ---------------------------------------------------------------------------
// bf16x3 MFMA split-K GEMM, pure-load staging from pre-split planes.
// Cp[z] = A[M,Kslice_z] @ W[N,Kslice_z]^T (+bias if z==0)
// A planes selected per n-block: n0<512 -> Aq planes, else Akv planes
// (enables merged cross-attn q+kv GEMM; harmless when Aq==Akv).
// Tile 64x64, K-step 64, 256 thr = 4 waves; wave w owns rows 16w..16w+15.
// mfma_f32_16x16x32_bf16: D col=l&15, row=(l>>4)*4+r  [m89-verified layout]
// ---------------------------------------------------------------------------
__global__ __launch_bounds__(256, 2) void gemm3p(
    const ushort* __restrict__ AqH, const ushort* __restrict__ AqL,
    const ushort* __restrict__ AkH, const ushort* __restrict__ AkL, int lda,
    const ushort* __restrict__ WH, const ushort* __restrict__ WL,
    const float* __restrict__ bias,
    float* __restrict__ C, int ldc, size_t pstride, int K, int Kslice)
{
    __shared__ ushort Ah[64][72], Al[64][72], Wh[64][72], Wl[64][72];
    const int tid = threadIdx.x;
    const int l = tid & 63, w = tid >> 6;
    const int m0 = blockIdx.x * 64, n0 = blockIdx.y * 64;
    const int z = blockIdx.z;
    const int srow = tid >> 2;            // 0..63
    const int skb = (tid & 3) << 4;       // 0,16,32,48 (ushort units)
    const ushort* AH = (n0 < 512) ? AqH : AkH;
    const ushort* AL = (n0 < 512) ? AqL : AkL;
    const ushort* ArH = AH + (size_t)(m0 + srow) * lda;
    const ushort* ArL = AL + (size_t)(m0 + srow) * lda;
    const ushort* WrH = WH + (size_t)(n0 + srow) * K;
    const ushort* WrL = WL + (size_t)(n0 + srow) * K;

    f32x4 acc[4];
#pragma unroll
    for (int ns = 0; ns < 4; ns++) acc[ns] = (f32x4)0.f;

    const int kbeg = z * Kslice, kend = kbeg + Kslice;
    for (int k0 = kbeg; k0 < kend; k0 += 64) {
        const uint4 ah0 = *(const uint4*)(ArH + k0 + skb);
        const uint4 ah1 = *(const uint4*)(ArH + k0 + skb + 8);
        const uint4 al0 = *(const uint4*)(ArL + k0 + skb);
        const uint4 al1 = *(const uint4*)(ArL + k0 + skb + 8);
        const uint4 wh0 = *(const uint4*)(WrH + k0 + skb);
        const uint4 wh1 = *(const uint4*)(WrH + k0 + skb + 8);
        const uint4 wl0 = *(const uint4*)(WrL + k0 + skb);
        const uint4 wl1 = *(const uint4*)(WrL + k0 + skb + 8);
        __syncthreads();
        *(uint4*)&Ah[srow][skb] = ah0; *(uint4*)&Ah[srow][skb + 8] = ah1;
        *(uint4*)&Al[srow][skb] = al0; *(uint4*)&Al[srow][skb + 8] = al1;
        *(uint4*)&Wh[srow][skb] = wh0; *(uint4*)&Wh[srow][skb + 8] = wh1;
        *(uint4*)&Wl[srow][skb] = wl0; *(uint4*)&Wl[srow][skb + 8] = wl1;
        __syncthreads();
        const int fr = l & 15, fg = (l >> 4) << 3;
#pragma unroll
        for (int ks = 0; ks < 2; ks++) {
            const short8 a_h = *(const short8*)&Ah[16 * w + fr][32 * ks + fg];
            const short8 a_l = *(const short8*)&Al[16 * w + fr][32 * ks + fg];
#pragma unroll
            for (int ns = 0; ns < 4; ns++) {
                const short8 b_h = *(const short8*)&Wh[16 * ns + fr][32 * ks + fg];
                const short8 b_l = *(const short8*)&Wl[16 * ns + fr][32 * ks + fg];
                acc[ns] = __builtin_amdgcn_mfma_f32_16x16x32_bf16(a_h, b_h, acc[ns], 0, 0, 0);
                acc[ns] = __builtin_amdgcn_mfma_f32_16x16x32_bf16(a_h, b_l, acc[ns], 0, 0, 0);
                acc[ns] = __builtin_amdgcn_mfma_f32_16x16x32_bf16(a_l, b_h, acc[ns], 0, 0, 0);
            }
        }
    }

    float* Cz = C + z * pstride;
    const int fr = l & 15, r4 = (l >> 4) << 2;
#pragma unroll
    for (int ns = 0; ns < 4; ns++) {
        const int col = n0 + 16 * ns + fr;
        const float bc = (bias && z == 0) ? bias[col] : 0.f;
#pragma unroll
        for (int r = 0; r < 4; r++) {
            const int row = m0 + 16 * w + r4 + r;
            Cz[(size_t)row * ldc + col] = acc[ns][r] + bc;
        }
    }
}

// ---------------------------------------------------------------------------
// f32 split-K tiled GEMM (encoder only)
// ---------------------------------------------------------------------------
__global__ __launch_bounds__(256, 2) void gemm_nt(
    const float* __restrict__ A, const int* __restrict__ Aidx, int lda,
    const float* __restrict__ W, const float* __restrict__ bias,
    float* __restrict__ C, int ldc, size_t pstride, int K, int Kslice)
{
    __shared__ float As[16][68];
    __shared__ float Ws[16][68];
    const int tid = threadIdx.x;
    const int tx = tid & 15, ty = tid >> 4;
    const int m0 = blockIdx.x * 64, n0 = blockIdx.y * 64;
    const int z = blockIdx.z;
    const int lrow = tid >> 2;
    const int lk = (tid & 3) << 2;
    const float* Arow;
    if (Aidx) Arow = A + (size_t)Aidx[m0 + lrow] * lda;
    else      Arow = A + (size_t)(m0 + lrow) * lda;
    const float* Wrow = W + (size_t)(n0 + lrow) * K;

    float acc[4][4];
#pragma unroll
    for (int i = 0; i < 4; i++)
#pragma unroll
        for (int j = 0; j < 4; j++) acc[i][j] = 0.f;

    const int kbeg = z * Kslice, kend = kbeg + Kslice;
    for (int k0 = kbeg; k0 < kend; k0 += 16) {
        const float4 av = *(const float4*)(Arow + k0 + lk);
        const float4 wv = *(const float4*)(Wrow + k0 + lk);
        __syncthreads();
        As[lk + 0][lrow] = av.x; As[lk + 1][lrow] = av.y;
        As[lk + 2][lrow] = av.z; As[lk + 3][lrow] = av.w;
        Ws[lk + 0][lrow] = wv.x; Ws[lk + 1][lrow] = wv.y;
        Ws[lk + 2][lrow] = wv.z; Ws[lk + 3][lrow] = wv.w;
        __syncthreads();
#pragma unroll
        for (int k = 0; k < 16; k++) {
            const float4 a = *(const float4*)(&As[k][ty << 2]);
            const float4 bq = *(const float4*)(&Ws[k][tx << 2]);
            acc[0][0] += a.x * bq.x; acc[0][1] += a.x * bq.y; acc[0][2] += a.x * bq.z; acc[0][3] += a.x * bq.w;
            acc[1][0] += a.y * bq.x; acc[1][1] += a.y * bq.y; acc[1][2] += a.y * bq.z; acc[1][3] += a.y * bq.w;
            acc[2][0] += a.z * bq.x; acc[2][1] += a.z * bq.y; acc[2][2] += a.z * bq.z; acc[2][3] += a.z * bq.w;
            acc[3][0] += a.w * bq.x; acc[3][1] += a.w * bq.y; acc[3][2] += a.w * bq.z; acc[3][3] += a.w * bq.w;
        }
    }

    float4 bv = make_float4(0.f, 0.f, 0.f, 0.f);
    if (bias && z == 0) bv = *(const float4*)(bias + n0 + (tx << 2));
    float* Cz = C + z * pstride;
#pragma unroll
    for (int i = 0; i < 4; i++) {
        const int r = m0 + (ty << 2) + i;
        float4 o;
        o.x = acc[i][0] + bv.x; o.y = acc[i][1] + bv.y;
        o.z = acc[i][2] + bv.z; o.w = acc[i][3] + bv.w;
        *(float4*)(Cz + (size_t)r * ldc + n0 + (tx << 2)) = o;
    }
}

// out[i] = sum_z Pz[i]  (encoder epilogues)
__global__ __launch_bounds__(256) void reduce_kernel(
    const float* __restrict__ P, size_t pstride,
    float* __restrict__ out, int n4, int znum)
{
    int i = blockIdx.x * 256 + threadIdx.x;
    const int stride = gridDim.x * 256;
    for (; i < n4; i += stride) {
        float4 o = ((const float4*)P)[i];
        for (int zz = 1; zz < znum; zz++) {
            const float4 b = ((const float4*)(P + zz * pstride))[i];
            o.x += b.x; o.y += b.y; o.z += b.z; o.w += b.w;
        }
        ((float4*)out)[i] = o;
    }
}

// ffbr planes = split(relu(P0 + P1))   (FFN intermediate)
__global__ __launch_bounds__(256) void fixrelu_kernel(
    const float* __restrict__ P, size_t pstride,
    ushort* __restrict__ H, ushort* __restrict__ L, int n4)
{
    int i = blockIdx.x * 256 + threadIdx.x;
    const int stride = gridDim.x * 256;
    for (; i < n4; i += stride) {
        const float4 a = ((const float4*)P)[i];
        const float4 b = ((const float4*)(P + pstride))[i];
        float4 o;
        o.x = fmaxf(a.x + b.x, 0.f); o.y = fmaxf(a.y + b.y, 0.f);
        o.z = fmaxf(a.z + b.z, 0.f); o.w = fmaxf(a.w + b.w, 0.f);
        ushort4 h, l;
        split4(o, h, l);
        ((ushort4*)H)[i] = h;
        ((ushort4*)L)[i] = l;
    }
}

// ---------------------------------------------------------------------------
// Attention over split-K qkv partials. Writes f32 out AND hi/lo planes.
// ---------------------------------------------------------------------------
template<int TK, int MODE, int NZ>
__global__ __launch_bounds__(256) void attn_kernel(
    const float* __restrict__ qkvP, size_t pstride,
    float* __restrict__ out, ushort* __restrict__ outH, ushort* __restrict__ outL,
    int T, int cur)
{
    __shared__ float KVs[TK][68];
    __shared__ float Qs[16][68];
    __shared__ float Ps[16][TK + 4];
    const int tid = threadIdx.x;
    const int tx = tid & 15, ty = tid >> 4;
    const int q0 = blockIdx.x * 16;
    const int h = blockIdx.y, b = blockIdx.z;
    const size_t base = (size_t)b * T * 1536 + h * 64;

    for (int idx = tid; idx < TK * 16; idx += 256) {
        const int j = idx >> 4, d4 = (idx & 15) << 2;
        const float* p = qkvP + base + (size_t)j * 1536 + 512 + d4;
        float4 v = *(const float4*)p;
#pragma unroll
        for (int zz = 1; zz < NZ; zz++) {
            const float4 u = *(const float4*)(p + zz * pstride);
            v.x += u.x; v.y += u.y; v.z += u.z; v.w += u.w;
        }
        *(float4*)&KVs[j][d4] = v;
    }
    {
        const int j = tid >> 4, d4 = (tid & 15) << 2;
        const float* p = qkvP + base + (size_t)(q0 + j) * 1536 + d4;
        float4 v = *(const float4*)p;
#pragma unroll
        for (int zz = 1; zz < NZ; zz++) {
            const float4 u = *(const float4*)(p + zz * pstride);
            v.x += u.x; v.y += u.y; v.z += u.z; v.w += u.w;
        }
        *(float4*)&Qs[j][d4] = v;
    }
    __syncthreads();

    const int qpos = q0 + ty;
    constexpr int NJ = TK >> 4;
    float s[NJ];
#pragma unroll
    for (int jj = 0; jj < NJ; jj++) {
        const int j = tx + (jj << 4);
        float acc = 0.f;
#pragma unroll
        for (int d = 0; d < 64; d += 4) {
            const float4 qv = *(const float4*)(&Qs[ty][d]);
            const float4 kv = *(const float4*)(&KVs[j][d]);
            acc += qv.x * kv.x + qv.y * kv.y + qv.z * kv.z + qv.w * kv.w;
        }
        acc *= 0.125f;
        if (MODE == 1 && j > qpos) acc += -1e9f;
        if (MODE == 2 && j >= cur) acc += -1e9f;
        s[jj] = acc;
    }
    float m = s[0];
#pragma unroll
    for (int jj = 1; jj < NJ; jj++) m = fmaxf(m, s[jj]);
#pragma unroll
    for (int o = 8; o >= 1; o >>= 1) m = fmaxf(m, __shfl_xor(m, o, 16));
    float sum = 0.f;
#pragma unroll
    for (int jj = 0; jj < NJ; jj++) {
        const float e = expf(s[jj] - m);
        s[jj] = e;
        sum += e;
    }
#pragma unroll
    for (int o = 8; o >= 1; o >>= 1) sum += __shfl_xor(sum, o, 16);
    const float inv = 1.f / sum;

    __syncthreads();  // all K reads done; reuse KVs for V

    for (int idx = tid; idx < TK * 16; idx += 256) {
        const int j = idx >> 4, d4 = (idx & 15) << 2;
        const float* p = qkvP + base + (size_t)j * 1536 + 1024 + d4;
        float4 v = *(const float4*)p;
#pragma unroll
        for (int zz = 1; zz < NZ; zz++) {
            const float4 u = *(const float4*)(p + zz * pstride);
            v.x += u.x; v.y += u.y; v.z += u.z; v.w += u.w;
        }
        *(float4*)&KVs[j][d4] = v;
    }
#pragma unroll
    for (int jj = 0; jj < NJ; jj++) Ps[ty][tx + (jj << 4)] = s[jj] * inv;
    __syncthreads();

    float4 o4 = make_float4(0.f, 0.f, 0.f, 0.f);
#pragma unroll 4
    for (int j = 0; j < TK; j++) {
        const float p = Ps[ty][j];
        const float4 v = *(const float4*)(&KVs[j][tx << 2]);
        o4.x = fmaf(p, v.x, o4.x); o4.y = fmaf(p, v.y, o4.y);
        o4.z = fmaf(p, v.z, o4.z); o4.w = fmaf(p, v.w, o4.w);
    }
    const size_t oidx = (size_t)(b * T + q0 + ty) * EE + h * 64 + (tx << 2);
    *(float4*)(out + oidx) = o4;
    ushort4 oh, ol;
    split4(o4, oh, ol);
    *(ushort4*)(outH + oidx) = oh;
    *(ushort4*)(outL + oidx) = ol;
}

// out = LN(X + sum4(SaP)) * g + b ; also writes hi/lo planes
__global__ __launch_bounds__(64) void resln_kernel(
    const float* __restrict__ X, const float* __restrict__ SaP, size_t pstride,
    const float* __restrict__ g, const float* __restrict__ bta,
    float* __restrict__ out, ushort* __restrict__ outH, ushort* __restrict__ outL)
{
    const int r = blockIdx.x;
    const int l = threadIdx.x;
    const float* xr = X + (size_t)r * EE;
    const float* sr = SaP + (size_t)r * EE;
    float4 v[2];
    float sum = 0.f;
#pragma unroll
    for (int p = 0; p < 2; p++) {
        const int o = p * 256 + l * 4;
        const float4 a = *(const float4*)(xr + o);
        const float4 c0 = *(const float4*)(sr + o);
        const float4 c1 = *(const float4*)(sr + pstride + o);
        const float4 c2 = *(const float4*)(sr + 2 * pstride + o);
        const float4 c3 = *(const float4*)(sr + 3 * pstride + o);
        v[p] = make_float4(a.x + c0.x + c1.x + c2.x + c3.x,
                           a.y + c0.y + c1.y + c2.y + c3.y,
                           a.z + c0.z + c1.z + c2.z + c3.z,
                           a.w + c0.w + c1.w + c2.w + c3.w);
        sum += v[p].x + v[p].y + v[p].z + v[p].w;
    }
#pragma unroll
    for (int o = 32; o >= 1; o >>= 1) sum += __shfl_xor(sum, o, 64);
    const float mean = sum * (1.f / EE);
    float vs = 0.f;
#pragma unroll
    for (int p = 0; p < 2; p++) {
        const float dx = v[p].x - mean, dy = v[p].y - mean;
        const float dz = v[p].z - mean, dw = v[p].w - mean;
        vs += dx * dx + dy * dy + dz * dz + dw * dw;
    }
#pragma unroll
    for (int o = 32; o >= 1; o >>= 1) vs += __shfl_xor(vs, o, 64);
    const float rstd = 1.f / sqrtf(vs * (1.f / EE) + 1e-5f);
#pragma unroll
    for (int p = 0; p < 2; p++) {
        const int o = p * 256 + l * 4;
        const float4 gv = *(const float4*)(g + o);
        const float4 bv = *(const float4*)(bta + o);
        float4 ov;
        ov.x = (v[p].x - mean) * rstd * gv.x + bv.x;
        ov.y = (v[p].y - mean) * rstd * gv.y + bv.y;
        ov.z = (v[p].z - mean) * rstd * gv.z + bv.z;
        ov.w = (v[p].w - mean) * rstd * gv.w + bv.w;
        const size_t oi = (size_t)r * EE + o;
        *(float4*)(out + oi) = ov;
        ushort4 oh, olo;
        split4(ov, oh, olo);
        *(ushort4*)(outH + oi) = oh;
        *(ushort4*)(outL + oi) = olo;
    }
}

// src = LN(embedding[seq] + pos_emb[s])  (encoder, f32 only)
__global__ __launch_bounds__(64) void embed_ln_kernel(
    const int* __restrict__ seq, const float* __restrict__ emb,
    const float* __restrict__ pemb, const float* __restrict__ g,
    const float* __restrict__ bta, float* __restrict__ out)
{
    const int r = blockIdx.x;
    const int s = r & (SS - 1);
    const int l = threadIdx.x;
    const int tok = seq[r];
    const float* er = emb + (size_t)tok * EE;
    const float* pr = pemb + (size_t)s * EE;
    float4 v[2];
    float sum = 0.f;
#pragma unroll
    for (int p = 0; p < 2; p++) {
        const int o = p * 256 + l * 4;
        const float4 a = *(const float4*)(er + o);
        const float4 c = *(const float4*)(pr + o);
        v[p] = make_float4(a.x + c.x, a.y + c.y, a.z + c.z, a.w + c.w);
        sum += v[p].x + v[p].y + v[p].z + v[p].w;
    }
#pragma unroll
    for (int o = 32; o >= 1; o >>= 1) sum += __shfl_xor(sum, o, 64);
    const float mean = sum * (1.f / EE);
    float vs = 0.f;
#pragma unroll
    for (int p = 0; p < 2; p++) {
        const float dx = v[p].x - mean, dy = v[p].y - mean;
        const float dz = v[p].z - mean, dw = v[p].w - mean;
        vs += dx * dx + dy * dy + dz * dz + dw * dw;
    }
#pragma unroll
    for (int o = 32; o >= 1; o >>= 1) vs += __shfl_xor(vs, o, 64);
    const float rstd = 1.f / sqrtf(vs * (1.f / EE) + 1e-5f);
#pragma unroll
    for (int p = 0; p < 2; p++) {
        const int o = p * 256 + l * 4;
        const float4 gv = *(const float4*)(g + o);
        const float4 bv = *(const float4*)(bta + o);
        float4 ov;
        ov.x = (v[p].x - mean) * rstd * gv.x + bv.x;
        ov.y = (v[p].y - mean) * rstd * gv.y + bv.y;
        ov.z = (v[p].z - mean) * rstd * gv.z + bv.z;
        ov.w = (v[p].w - mean) * rstd * gv.w + bv.w;
        *(float4*)(out + (size_t)r * EE + o) = ov;
    }
}

// buf[:, :S] = xe ; buf[:, S:] = 0 ; also fills buf hi/lo planes
__global__ __launch_bounds__(256) void bufinit_kernel(
    const float* __restrict__ xe, float* __restrict__ buf,
    ushort* __restrict__ bufH, ushort* __restrict__ bufL)
{
    const int i = blockIdx.x * 256 + threadIdx.x;   // float4 index
    if (i >= BB * TT * EE / 4) return;
    const int g = i * 4;
    const int e = g & (EE - 1);
    const int t = (g >> 9) % TT;
    const int b = g / (EE * TT);
    float4 v = make_float4(0.f, 0.f, 0.f, 0.f);
    if (t < SS) v = *(const float4*)(xe + ((size_t)b * SS + t) * EE + e);
    ((float4*)buf)[i] = v;
    ushort4 h, l;
    split4(v, h, l);
    ((ushort4*)bufH)[i] = h;
    ((ushort4*)bufL)[i] = l;
}

// logits[b][col] = dot(tgt[b, cur-1, :], fo_w[col, :]) + fo_b[col]
__global__ __launch_bounds__(256) void logits_kernel(
    const float* __restrict__ tgt, const float* __restrict__ foW,
    const float* __restrict__ fob, float* __restrict__ logits, int cur)
{
    __shared__ float last_s[BB][EE];
    const int tid = threadIdx.x;
    for (int idx = tid; idx < BB * EE; idx += 256) {
        const int b = idx >> 9, e = idx & (EE - 1);
        last_s[b][e] = tgt[((size_t)b * TT + (cur - 1)) * EE + e];
    }
    __syncthreads();
    const int w = tid >> 6, l = tid & 63;
    const int col = blockIdx.x * 4 + w;
    float a0 = 0.f, a1 = 0.f, a2 = 0.f, a3 = 0.f;
    const float* wr = foW + (size_t)col * EE;
#pragma unroll
    for (int p = 0; p < 2; p++) {
        const int o = p * 256 + l * 4;
        const float4 wv = *(const float4*)(wr + o);
        const float4 l0 = *(const float4*)(&last_s[0][o]);
        const float4 l1 = *(const float4*)(&last_s[1][o]);
        const float4 l2 = *(const float4*)(&last_s[2][o]);
        const float4 l3 = *(const float4*)(&last_s[3][o]);
        a0 += wv.x * l0.x + wv.y * l0.y + wv.z * l0.z + wv.w * l0.w;
        a1 += wv.x * l1.x + wv.y * l1.y + wv.z * l1.z + wv.w * l1.w;
        a2 += wv.x * l2.x + wv.y * l2.y + wv.z * l2.z + wv.w * l2.w;
        a3 += wv.x * l3.x + wv.y * l3.y + wv.z * l3.z + wv.w * l3.w;
    }
#pragma unroll
    for (int o = 32; o >= 1; o >>= 1) {
        a0 += __shfl_xor(a0, o, 64); a1 += __shfl_xor(a1, o, 64);
        a2 += __shfl_xor(a2, o, 64); a3 += __shfl_xor(a3, o, 64);
    }
    if (l == 0) {
        const float bb = fob[col];
        logits[(size_t)0 * VV + col] = a0 + bb;
        logits[(size_t)1 * VV + col] = a1 + bb;
        logits[(size_t)2 * VV + col] = a2 + bb;
        logits[(size_t)3 * VV + col] = a3 + bb;
    }
}

// argmax (first-index tie-break), write token, append embedding row (f32+planes)
__global__ __launch_bounds__(256) void argmax_kernel(
    const float* __restrict__ logits, const float* __restrict__ emb,
    float* __restrict__ buf, ushort* __restrict__ bufH, ushort* __restrict__ bufL,
    int* __restrict__ out_tok, int cur, int step)
{
    __shared__ float sv[256];
    __shared__ int si[256];
    const int b = blockIdx.x;
    const int tid = threadIdx.x;
    float best = -3.4e38f;
    int bi = 0x7fffffff;
    for (int v = tid; v < VV; v += 256) {
        const float x = logits[(size_t)b * VV + v];
        if (x > best) { best = x; bi = v; }
    }
    sv[tid] = best; si[tid] = bi;
    __syncthreads();
    for (int s = 128; s > 0; s >>= 1) {
        if (tid < s) {
            const float xo = sv[tid + s]; const int io = si[tid + s];
            if (xo > sv[tid] || (xo == sv[tid] && io < si[tid])) { sv[tid] = xo; si[tid] = io; }
        }
        __syncthreads();
    }
    const int tok = si[0];
    if (tid == 0) out_tok[b * MM + step] = tok;
    if (tid < EE / 4) {
        const float4 v = *(const float4*)(emb + (size_t)tok * EE + tid * 4);
        const size_t oi = ((size_t)b * TT + cur) * EE + tid * 4;
        *(float4*)(buf + oi) = v;
        ushort4 h, l;
        split4(v, h, l);
        *(ushort4*)(bufH + oi) = h;
        *(ushort4*)(bufL + oi) = l;
    }
}

extern "C" void kernel_launch(void* const* d_in, const int* in_sizes, int n_in,
                              void* d_out, int out_size, void* d_ws, size_t ws_size,
                              hipStream_t stream)
{
    (void)in_sizes; (void)n_in; (void)out_size; (void)ws_size;
    const int*   seq   = (const int*)d_in[0];
    const int*   ptag  = (const int*)d_in[1];
    const int*   ntag  = (const int*)d_in[2];
    const float* emb   = (const float*)d_in[4];
    const float* pemb  = (const float*)d_in[5];
    const float* fcp_w = (const float*)d_in[6];
    const float* fcp_b = (const float*)d_in[7];
    const float* fcn_w = (const float*)d_in[8];
    const float* fcn_b = (const float*)d_in[9];
    const float* ln_g  = (const float*)d_in[10];
    const float* ln_b  = (const float*)d_in[11];
    const float* asi_w = (const float*)d_in[12];
    const float* asi_b = (const float*)d_in[13];
    const float* aso_w = (const float*)d_in[14];
    const float* aso_b = (const float*)d_in[15];
    const float* api_w = (const float*)d_in[16];
    const float* api_b = (const float*)d_in[17];
    const float* apo_w = (const float*)d_in[18];
    const float* apo_b = (const float*)d_in[19];
    const float* ani_w = (const float*)d_in[20];
    const float* ani_b = (const float*)d_in[21];
    const float* ano_w = (const float*)d_in[22];
    const float* ano_b = (const float*)d_in[23];
    const float* dsi_w = (const float*)d_in[24];
    const float* dsi_b = (const float*)d_in[25];
    const float* dso_w = (const float*)d_in[26];
    const float* dso_b = (const float*)d_in[27];
    const float* dci_w = (const float*)d_in[28];
    const float* dci_b = (const float*)d_in[29];
    const float* dco_w = (const float*)d_in[30];
    const float* dco_b = (const float*)d_in[31];
    const float* d1_w  = (const float*)d_in[32];
    const float* d1_b  = (const float*)d_in[33];
    const float* d2_w  = (const float*)d_in[34];
    const float* d2_b  = (const float*)d_in[35];
    const float* dln_g = (const float*)d_in[36];
    const float* dln_b = (const float*)d_in[37];
    const float* fo_w  = (const float*)d_in[38];
    const float* fo_b  = (const float*)d_in[39];
    int* out_tok = (int*)d_out;

    // ---- workspace layout (ushort units from base) ----
    ushort* us = (ushort*)d_ws;
    ushort* whi  = us;                       // 8,388,608
    ushort* wlo  = whi + 8388608;            // 8,388,608
    ushort* bufH = wlo + 8388608;            // 294,912
    ushort* bufL = bufH + 294912;
    ushort* tgtH = bufL + 294912;
    ushort* tgtL = tgtH + 294912;
    ushort* attH = tgtL + 294912;
    ushort* attL = attH + 294912;
    ushort* ffbH = attL + 294912;            // 1,179,648
    ushort* ffbL = ffbH + 1179648;
    // weight plane offsets
    const size_t o_dsi = 0;
    const size_t o_dso = 1572864;
    const size_t o_dci = 2097152;
    const size_t o_dco = 3670016;
    const size_t o_d1  = 4194304;
    const size_t o_d2  = 6291456;
    // f32 arena
    float* arena = (float*)(ffbL + 1179648);
    float* P    = arena;                     // 3,145,728
    float* sabP = P + 3145728;               // 1,179,648
    float* att  = sabP + 1179648;            // 294,912
    float* tgt  = att + 294912;              // 294,912
    float* buf  = tgt + 294912;              // 294,912
    float* lg   = buf + 294912;              // 128,000
    // encoder-phase aliases (sabP region is free during encoder)
    float* src = sabP;
    float* xe  = sabP + 262144;
    float* pf  = sabP + 524288;
    float* nf  = sabP + 786432;

    const int RS = BB * SS;   // 512
    const int RT = BB * TT;   // 576
    const size_t psE  = (size_t)RS * EE;     // 262,144
    const size_t psEq = (size_t)RS * 1536;   // 786,432
    const size_t psD  = (size_t)RT * EE;     // 294,912
    const size_t psDq = (size_t)RT * 1536;   // 884,736
    const size_t psF  = (size_t)RT * FFF;    // 1,179,648

    // ---- one-time: split decoder weights into bf16 hi/lo planes ----
    split_kernel<<<512, 256, 0, stream>>>(dsi_w, whi + o_dsi, wlo + o_dsi, 1572864 / 4);
    split_kernel<<<256, 256, 0, stream>>>(dso_w, whi + o_dso, wlo + o_dso, 524288 / 4);
    split_kernel<<<512, 256, 0, stream>>>(dci_w, whi + o_dci, wlo + o_dci, 1572864 / 4);
    split_kernel<<<256, 256, 0, stream>>>(dco_w, whi + o_dco, wlo + o_dco, 524288 / 4);
    split_kernel<<<512, 256, 0, stream>>>(d1_w, whi + o_d1, wlo + o_d1, 2097152 / 4);
    split_kernel<<<512, 256, 0, stream>>>(d2_w, whi + o_d2, wlo + o_d2, 2097152 / 4);

    // ---------------- encoder (f32 path, runs once) ----------------
    embed_ln_kernel<<<RS, 64, 0, stream>>>(seq, emb, pemb, ln_g, ln_b, src);
    gemm_nt<<<dim3(RS / 64, 8, 4), 256, 0, stream>>>(emb, ptag, EE, fcp_w, fcp_b, P, EE, psE, EE, 128);
    reduce_kernel<<<256, 256, 0, stream>>>(P, psE, pf, 65536, 4);
    gemm_nt<<<dim3(RS / 64, 8, 4), 256, 0, stream>>>(emb, ntag, EE, fcn_w, fcn_b, P, EE, psE, EE, 128);
    reduce_kernel<<<256, 256, 0, stream>>>(P, psE, nf, 65536, 4);
    gemm_nt<<<dim3(RS / 64, 24, 4), 256, 0, stream>>>(src, nullptr, EE, asi_w, asi_b, P, 1536, psEq, EE, 128);
    attn_kernel<SS, 0, 4><<<dim3(SS / 16, HH, BB), 256, 0, stream>>>(P, psEq, att, attH, attL, SS, 0);
    gemm_nt<<<dim3(RS / 64, 8, 4), 256, 0, stream>>>(att, nullptr, EE, aso_w, aso_b, P, EE, psE, EE, 128);
    reduce_kernel<<<256, 256, 0, stream>>>(P, psE, xe, 65536, 4);
    gemm_nt<<<dim3(RS / 64, 8, 4), 256, 0, stream>>>(xe, nullptr, EE, api_w, api_b, P, 1536, psEq, EE, 128);
    gemm_nt<<<dim3(RS / 64, 16, 4), 256, 0, stream>>>(pf, nullptr, EE, api_w + 512 * EE, api_b + 512, P + 512, 1536, psEq, EE, 128);
    attn_kernel<SS, 0, 4><<<dim3(SS / 16, HH, BB), 256, 0, stream>>>(P, psEq, att, attH, attL, SS, 0);
    gemm_nt<<<dim3(RS / 64, 8, 4), 256, 0, stream>>>(att, nullptr, EE, apo_w, apo_b, P, EE, psE, EE, 128);
    reduce_kernel<<<256, 256, 0, stream>>>(P, psE, src, 65536, 4);
    gemm_nt<<<dim3(RS / 64, 8, 4), 256, 0, stream>>>(src, nullptr, EE, ani_w, ani_b, P, 1536, psEq, EE, 128);
    gemm_nt<<<dim3(RS / 64, 16, 4), 256, 0, stream>>>(nf, nullptr, EE, ani_w + 512 * EE, ani_b + 512, P + 512, 1536, psEq, EE, 128);
    attn_kernel<SS, 0, 4><<<dim3(SS / 16, HH, BB), 256, 0, stream>>>(P, psEq, att, attH, attL, SS, 0);
    gemm_nt<<<dim3(RS / 64, 8, 4), 256, 0, stream>>>(att, nullptr, EE, ano_w, ano_b, P, EE, psE, EE, 128);
    reduce_kernel<<<256, 256, 0, stream>>>(P, psE, xe, 65536, 4);
    bufinit_kernel<<<(BB * TT * EE / 4 + 255) / 256, 256, 0, stream>>>(xe, buf, bufH, bufL);

    // ---------------- decoder loop (bf16x3 MFMA, pre-split planes) ----------------
    for (int i = 0; i < MM; i++) {
        const int cur = SS + i;
        for (int l = 0; l < LL; l++) {
            const float*  tinF = (l == 0) ? buf  : tgt;
            const ushort* tinH = (l == 0) ? bufH : tgtH;
            const ushort* tinL = (l == 0) ? bufL : tgtL;
            const size_t wl1536 = (size_t)l * 1536 * EE;
            const size_t wl512  = (size_t)l * EE * EE;
            const size_t wlF    = (size_t)l * FFF * EE;
            // self-attn (causal)
            gemm3p<<<dim3(RT / 64, 24, 2), 256, 0, stream>>>(tinH, tinL, tinH, tinL, EE,
                whi + o_dsi + wl1536, wlo + o_dsi + wl1536, dsi_b + l * 1536, P, 1536, psDq, EE, 256);
            attn_kernel<TT, 1, 2><<<dim3(TT / 16, HH, BB), 256, 0, stream>>>(P, psDq, att, attH, attL, TT, 0);
            gemm3p<<<dim3(RT / 64, 8, 4), 256, 0, stream>>>(attH, attL, attH, attL, EE,
                whi + o_dso + wl512, wlo + o_dso + wl512, dso_b + l * EE, sabP, EE, psD, EE, 128);
            resln_kernel<<<RT, 64, 0, stream>>>(tinF, sabP, psD,
                dln_g + (l * 3 + 0) * EE, dln_b + (l * 3 + 0) * EE, tgt, tgtH, tgtL);
            // cross-attn: q from tgt planes, kv from buf planes — ONE merged dispatch
            gemm3p<<<dim3(RT / 64, 24, 2), 256, 0, stream>>>(tgtH, tgtL, bufH, bufL, EE,
                whi + o_dci + wl1536, wlo + o_dci + wl1536, dci_b + l * 1536, P, 1536, psDq, EE, 256);
            attn_kernel<TT, 2, 2><<<dim3(TT / 16, HH, BB), 256, 0, stream>>>(P, psDq, att, attH, attL, TT, cur);
            gemm3p<<<dim3(RT / 64, 8, 4), 256, 0, stream>>>(attH, attL, attH, attL, EE,
                whi + o_dco + wl512, wlo + o_dco + wl512, dco_b + l * EE, sabP, EE, psD, EE, 128);
            resln_kernel<<<RT, 64, 0, stream>>>(tgt, sabP, psD,
                dln_g + (l * 3 + 1) * EE, dln_b + (l * 3 + 1) * EE, tgt, tgtH, tgtL);
            // FFN
            gemm3p<<<dim3(RT / 64, 32, 2), 256, 0, stream>>>(tgtH, tgtL, tgtH, tgtL, EE,
                whi + o_d1 + wlF, wlo + o_d1 + wlF, d1_b + l * FFF, P, FFF, psF, EE, 256);
            fixrelu_kernel<<<1152, 256, 0, stream>>>(P, psF, ffbH, ffbL, 294912);
            gemm3p<<<dim3(RT / 64, 8, 4), 256, 0, stream>>>(ffbH, ffbL, ffbH, ffbL, FFF,
                whi + o_d2 + wlF, wlo + o_d2 + wlF, d2_b + l * EE, sabP, EE, psD, FFF, 512);
            resln_kernel<<<RT, 64, 0, stream>>>(tgt, sabP, psD,
                dln_g + (l * 3 + 2) * EE, dln_b + (l * 3 + 2) * EE, tgt, tgtH, tgtL);
        }
        logits_kernel<<<VV / 4, 256, 0, stream>>>(tgt, fo_w, fo_b, lg, cur);
        argmax_kernel<<<BB, 256, 0, stream>>>(lg, emb, buf, bufH, bufL, out_tok, cur, i);
    }
}